// Round 3
// baseline (2494.196 us; speedup 1.0000x reference)
//
#include <hip/hip_runtime.h>
#include <hip/hip_bf16.h>
#include <stdint.h>

#define DI __device__ __forceinline__

namespace {

constexpr int BB  = 256;   // batch
constexpr int LL  = 128;   // seq len
constexpr int DM  = 64;    // d_model
constexpr int NH  = 4;     // heads
constexpr int DFF = 512;   // ffn dim
constexpr int NL  = 6;     // layers
constexpr int TT  = BB * LL;  // 32768 tokens

// ---------- bf16 helpers ----------
DI float blo(uint32_t u) { union { uint32_t i; float f; } w; w.i = u << 16; return w.f; }
DI float bhi(uint32_t u) { union { uint32_t i; float f; } w; w.i = u & 0xffff0000u; return w.f; }
DI float bf2f(uint16_t u) { union { uint32_t i; float f; } w; w.i = (uint32_t)u << 16; return w.f; }
DI uint16_t f2bf(float f) {
  union { float f; uint32_t i; } w; w.f = f;
  uint32_t r = (w.i + 0x7fffu + ((w.i >> 16) & 1u)) >> 16;  // RNE
  return (uint16_t)r;
}
DI uint32_t pack2(float a, float b) { return (uint32_t)f2bf(a) | ((uint32_t)f2bf(b) << 16); }

// load 64 f32 (one token row) into regs
DI void load_row_f32(const float* __restrict__ src, float* xr) {
#pragma unroll
  for (int q = 0; q < 16; ++q) {
    float4 v = *(const float4*)(src + 4 * q);
    xr[4*q+0] = v.x; xr[4*q+1] = v.y; xr[4*q+2] = v.z; xr[4*q+3] = v.w;
  }
}
// load 64 bf16 into f32 regs
DI void load_row_bf16(const uint16_t* __restrict__ src, float* xr) {
#pragma unroll
  for (int q = 0; q < 8; ++q) {
    uint4 v = *(const uint4*)(src + 8 * q);
    xr[8*q+0] = blo(v.x); xr[8*q+1] = bhi(v.x);
    xr[8*q+2] = blo(v.y); xr[8*q+3] = bhi(v.y);
    xr[8*q+4] = blo(v.z); xr[8*q+5] = bhi(v.z);
    xr[8*q+6] = blo(v.w); xr[8*q+7] = bhi(v.w);
  }
}
// dot(xr[0..63], w-column). wc is wave-uniform -> scalar loads expected.
DI float dotcol(const float* __restrict__ wc, const float* xr) {
  const float4* w4 = (const float4*)wc;
  float a0 = 0.f, a1 = 0.f, a2 = 0.f, a3 = 0.f;
#pragma unroll
  for (int q = 0; q < 16; ++q) {
    float4 w = w4[q];
    a0 = fmaf(w.x, xr[4*q+0], a0);
    a1 = fmaf(w.y, xr[4*q+1], a1);
    a2 = fmaf(w.z, xr[4*q+2], a2);
    a3 = fmaf(w.w, xr[4*q+3], a3);
  }
  return (a0 + a1) + (a2 + a3);
}

// ---------- setup kernels ----------
// x[t][d] = src_emb[enc[t]][d] + deg_emb[deg[t]][d] + pe[l][d]   (f32)
__global__ void __launch_bounds__(256) k_embed(const int* __restrict__ enc, const int* __restrict__ deg,
    const float* __restrict__ semb, const float* __restrict__ demb, float* __restrict__ x) {
  int idx = blockIdx.x * 256 + threadIdx.x;   // T*64
  int t = idx >> 6, d = idx & 63;
  int l = t & (LL - 1);
  float e = (float)(d & ~1) * -0.14391156831212787f;   // -ln(10000)/64
  float ang = (float)l * __expf(e);
  float pe = (d & 1) ? __cosf(ang) : __sinf(ang);
  x[idx] = semb[enc[t] * DM + d] + demb[deg[t] * DM + d] + pe;
}

// wt[mat][c][k] = w[mat][k][c]   (transpose, so GEMM weight loads are contiguous per column)
__global__ void __launch_bounds__(256) k_trans(const float* __restrict__ w, float* __restrict__ wt,
    int K, int O, int KO) {
  int idx = blockIdx.x * 256 + threadIdx.x;
  int mat = idx / KO;
  int rem = idx - mat * KO;
  int c = rem / K;
  int k = rem - c * K;
  wt[idx] = w[(mat * K + k) * O + c];
}

// bias[b][kk][row][h] (bf16 x4 = uint2) = mask ? -1e9 : md_emb[MD[b,row,kk]][h]
__global__ void __launch_bounds__(256) k_bias(const int* __restrict__ MD, const float* __restrict__ memb,
    const int* __restrict__ enc, uint2* __restrict__ bias) {
  int o = blockIdx.x * 256 + threadIdx.x;   // enumerates (b, kk, row)
  int b   = o >> 14;
  int kk  = (o >> 7) & (LL - 1);
  int row = o & (LL - 1);
  uint2 e;
  if (enc[b * LL + kk] == 0) {
    e.x = 0xce6ece6eu; e.y = 0xce6ece6eu;   // bf16(-1e9) packed x4
  } else {
    int v = MD[(b * LL + row) * LL + kk];
    float4 m = *(const float4*)(memb + v * 4);
    e.x = pack2(m.x, m.y); e.y = pack2(m.z, m.w);
  }
  bias[o] = e;
}

// ---------- per-layer kernels ----------
// qkv[t][seg*64 + c] = x[t][:] @ Wt_seg[c][:]    seg = blockIdx.y in {q,k,v}
__global__ void __launch_bounds__(256) k_qkv(const float* __restrict__ x,
    const float* __restrict__ wtq, const float* __restrict__ wtk, const float* __restrict__ wtv,
    uint16_t* __restrict__ qkv) {
  const float* wt = blockIdx.y == 0 ? wtq : (blockIdx.y == 1 ? wtk : wtv);
  int wv = blockIdx.x * 4 + (threadIdx.x >> 6);
  int lane = threadIdx.x & 63;
  int t = wv * 64 + lane;
  float xr[64];
  load_row_f32(x + (size_t)t * DM, xr);
  uint16_t* o = qkv + (size_t)t * 192 + blockIdx.y * 64;
  for (int c0 = 0; c0 < 64; c0 += 4) {
    float a0 = dotcol(wt + (c0 + 0) * DM, xr);
    float a1 = dotcol(wt + (c0 + 1) * DM, xr);
    float a2 = dotcol(wt + (c0 + 2) * DM, xr);
    float a3 = dotcol(wt + (c0 + 3) * DM, xr);
    uint2 pkt; pkt.x = pack2(a0, a1); pkt.y = pack2(a2, a3);
    *(uint2*)(o + c0) = pkt;
  }
}

// fused attention: wave = (b, h, row-half); softmax without max-shift (scores tiny; masked = -1e9 -> exp=0)
__global__ void __launch_bounds__(256) k_attn(const uint16_t* __restrict__ qkv,
    const uint16_t* __restrict__ bias, uint16_t* __restrict__ ctx) {
  int wv = blockIdx.x * 4 + (threadIdx.x >> 6);   // 0..2047
  int lane = threadIdx.x & 63;
  int b = wv >> 3;
  int h = (wv >> 1) & 3;
  int row = (wv & 1) * 64 + lane;
  int t = b * LL + row;

  float q[16];
  {
    const uint16_t* qp = qkv + (size_t)t * 192 + h * 16;
    uint4 a = *(const uint4*)qp;
    uint4 c = *(const uint4*)(qp + 8);
    q[0]=blo(a.x); q[1]=bhi(a.x); q[2]=blo(a.y); q[3]=bhi(a.y);
    q[4]=blo(a.z); q[5]=bhi(a.z); q[6]=blo(a.w); q[7]=bhi(a.w);
    q[8]=blo(c.x); q[9]=bhi(c.x); q[10]=blo(c.y); q[11]=bhi(c.y);
    q[12]=blo(c.z); q[13]=bhi(c.z); q[14]=blo(c.w); q[15]=bhi(c.w);
#pragma unroll
    for (int j = 0; j < 16; ++j) q[j] *= 0.25f;    // 1/sqrt(16)
  }
  float acc[16];
#pragma unroll
  for (int j = 0; j < 16; ++j) acc[j] = 0.f;
  float sum = 0.f;

  const uint16_t* kbase = qkv + (size_t)b * LL * 192 + 64 + h * 16;   // K rows (wave-uniform)
  const uint16_t* vbase = kbase + 64;                                  // V rows
  const uint16_t* bb = bias + ((size_t)b * LL * LL + row) * 4 + h;

#pragma unroll 2
  for (int kk = 0; kk < LL; ++kk) {
    const uint4* kr = (const uint4*)(kbase + kk * 192);
    uint4 ka = kr[0], kb2 = kr[1];
    float d0 = 0.f, d1 = 0.f, d2 = 0.f, d3 = 0.f;
    d0 = fmaf(q[0],  blo(ka.x),  d0);  d1 = fmaf(q[1],  bhi(ka.x),  d1);
    d2 = fmaf(q[2],  blo(ka.y),  d2);  d3 = fmaf(q[3],  bhi(ka.y),  d3);
    d0 = fmaf(q[4],  blo(ka.z),  d0);  d1 = fmaf(q[5],  bhi(ka.z),  d1);
    d2 = fmaf(q[6],  blo(ka.w),  d2);  d3 = fmaf(q[7],  bhi(ka.w),  d3);
    d0 = fmaf(q[8],  blo(kb2.x), d0);  d1 = fmaf(q[9],  bhi(kb2.x), d1);
    d2 = fmaf(q[10], blo(kb2.y), d2);  d3 = fmaf(q[11], bhi(kb2.y), d3);
    d0 = fmaf(q[12], blo(kb2.z), d0);  d1 = fmaf(q[13], bhi(kb2.z), d1);
    d2 = fmaf(q[14], blo(kb2.w), d2);  d3 = fmaf(q[15], bhi(kb2.w), d3);
    float s = ((d0 + d1) + (d2 + d3)) + bf2f(bb[(size_t)kk * 512]);
    float p = __expf(s);
    sum += p;
    const uint4* vr = (const uint4*)(vbase + kk * 192);
    uint4 va = vr[0], vb = vr[1];
    acc[0]  = fmaf(p, blo(va.x), acc[0]);   acc[1]  = fmaf(p, bhi(va.x), acc[1]);
    acc[2]  = fmaf(p, blo(va.y), acc[2]);   acc[3]  = fmaf(p, bhi(va.y), acc[3]);
    acc[4]  = fmaf(p, blo(va.z), acc[4]);   acc[5]  = fmaf(p, bhi(va.z), acc[5]);
    acc[6]  = fmaf(p, blo(va.w), acc[6]);   acc[7]  = fmaf(p, bhi(va.w), acc[7]);
    acc[8]  = fmaf(p, blo(vb.x), acc[8]);   acc[9]  = fmaf(p, bhi(vb.x), acc[9]);
    acc[10] = fmaf(p, blo(vb.y), acc[10]);  acc[11] = fmaf(p, bhi(vb.y), acc[11]);
    acc[12] = fmaf(p, blo(vb.z), acc[12]);  acc[13] = fmaf(p, bhi(vb.z), acc[13]);
    acc[14] = fmaf(p, blo(vb.w), acc[14]);  acc[15] = fmaf(p, bhi(vb.w), acc[15]);
  }
  float inv = 1.0f / sum;
  uint16_t* o = ctx + (size_t)t * DM + h * 16;
  uint4 o0, o1;
  o0.x = pack2(acc[0]*inv,  acc[1]*inv);   o0.y = pack2(acc[2]*inv,  acc[3]*inv);
  o0.z = pack2(acc[4]*inv,  acc[5]*inv);   o0.w = pack2(acc[6]*inv,  acc[7]*inv);
  o1.x = pack2(acc[8]*inv,  acc[9]*inv);   o1.y = pack2(acc[10]*inv, acc[11]*inv);
  o1.z = pack2(acc[12]*inv, acc[13]*inv);  o1.w = pack2(acc[14]*inv, acc[15]*inv);
  *(uint4*)o = o0;
  *(uint4*)(o + 8) = o1;
}

// y[t][cbase+c] = ctx[t][:] @ Wo_col   (16 cols per wave; grid.y = 4)
__global__ void __launch_bounds__(256) k_oproj(const uint16_t* __restrict__ a,
    const float* __restrict__ wt, uint16_t* __restrict__ y) {
  int wv = blockIdx.x * 4 + (threadIdx.x >> 6);
  int lane = threadIdx.x & 63;
  int t = wv * 64 + lane;
  float xr[64];
  load_row_bf16(a + (size_t)t * DM, xr);
  int cbase = blockIdx.y * 16;
  uint16_t* o = y + (size_t)t * DM + cbase;
  for (int c0 = 0; c0 < 16; c0 += 4) {
    float a0 = dotcol(wt + (cbase + c0 + 0) * DM, xr);
    float a1 = dotcol(wt + (cbase + c0 + 1) * DM, xr);
    float a2 = dotcol(wt + (cbase + c0 + 2) * DM, xr);
    float a3 = dotcol(wt + (cbase + c0 + 3) * DM, xr);
    uint2 pkt; pkt.x = pack2(a0, a1); pkt.y = pack2(a2, a3);
    *(uint2*)(o + c0) = pkt;
  }
}

// x[t][:] = LN(bf16(y[t][:]) + x[t][:])   wave per token, lane = d
__global__ void __launch_bounds__(256) k_addln(const uint16_t* __restrict__ y, float* __restrict__ x) {
  int wv = blockIdx.x * 4 + (threadIdx.x >> 6);
  int lane = threadIdx.x & 63;
  int i = wv * 64 + lane;
  float v = bf2f(y[i]) + x[i];
  float s = v;
#pragma unroll
  for (int off = 32; off > 0; off >>= 1) s += __shfl_xor(s, off, 64);
  float mu = s * 0.015625f;
  float d = v - mu;
  float s2 = d * d;
#pragma unroll
  for (int off = 32; off > 0; off >>= 1) s2 += __shfl_xor(s2, off, 64);
  x[i] = d * rsqrtf(s2 * 0.015625f + 1e-5f);
}

// hid[t][c] = relu(x[t][:] @ W1_col)   (128 cols per wave; grid.y = 4)
__global__ void __launch_bounds__(256) k_ffn1(const float* __restrict__ x,
    const float* __restrict__ wt, uint16_t* __restrict__ hid) {
  int wv = blockIdx.x * 4 + (threadIdx.x >> 6);
  int lane = threadIdx.x & 63;
  int t = wv * 64 + lane;
  float xr[64];
  load_row_f32(x + (size_t)t * DM, xr);
  int cbase = blockIdx.y * 128;
  uint16_t* o = hid + (size_t)t * DFF;
  for (int c0 = cbase; c0 < cbase + 128; c0 += 4) {
    float a0 = fmaxf(dotcol(wt + (c0 + 0) * DM, xr), 0.f);
    float a1 = fmaxf(dotcol(wt + (c0 + 1) * DM, xr), 0.f);
    float a2 = fmaxf(dotcol(wt + (c0 + 2) * DM, xr), 0.f);
    float a3 = fmaxf(dotcol(wt + (c0 + 3) * DM, xr), 0.f);
    uint2 pkt; pkt.x = pack2(a0, a1); pkt.y = pack2(a2, a3);
    *(uint2*)(o + c0) = pkt;
  }
}

// y[t][cbase+j] = hid[t][:] @ W2_col   (K = 512, chunked by 64; 16 cols per wave; grid.y = 4)
__global__ void __launch_bounds__(256) k_ffn2(const uint16_t* __restrict__ hid,
    const float* __restrict__ wt, uint16_t* __restrict__ y) {
  int wv = blockIdx.x * 4 + (threadIdx.x >> 6);
  int lane = threadIdx.x & 63;
  int t = wv * 64 + lane;
  int cbase = blockIdx.y * 16;
  float acc[16];
#pragma unroll
  for (int j = 0; j < 16; ++j) acc[j] = 0.f;
  for (int kc = 0; kc < DFF; kc += 64) {
    float xr[64];
    load_row_bf16(hid + (size_t)t * DFF + kc, xr);
#pragma unroll
    for (int j = 0; j < 16; ++j) {
      acc[j] += dotcol(wt + (size_t)(cbase + j) * DFF + kc, xr);
    }
  }
  uint16_t* o = y + (size_t)t * DM + cbase;
#pragma unroll
  for (int j = 0; j < 16; j += 4) {
    uint2 pkt; pkt.x = pack2(acc[j], acc[j+1]); pkt.y = pack2(acc[j+2], acc[j+3]);
    *(uint2*)(o + j) = pkt;
  }
}

// d_out is FLOAT32 (reference output dtype) — plain f32 copy of the residual stream
__global__ void __launch_bounds__(256) k_out(const float* __restrict__ x, float* __restrict__ out) {
  int i = blockIdx.x * 256 + threadIdx.x;
  out[i] = x[i];
}

} // namespace

extern "C" void kernel_launch(void* const* d_in, const int* in_sizes, int n_in,
                              void* d_out, int out_size, void* d_ws, size_t ws_size,
                              hipStream_t stream) {
  const int* enc = (const int*)d_in[0];
  const int* deg = (const int*)d_in[1];
  const int* MD  = (const int*)d_in[2];
  const float* semb = (const float*)d_in[3];   // inputs are float32 per the reference
  const float* demb = (const float*)d_in[4];
  const float* memb = (const float*)d_in[5];
  const float* Wq = (const float*)d_in[6];
  const float* Wk = (const float*)d_in[7];
  const float* Wv = (const float*)d_in[8];
  const float* Wo = (const float*)d_in[9];
  const float* W1 = (const float*)d_in[10];
  const float* W2 = (const float*)d_in[11];

  // ---- workspace layout (~94 MB) ----
  char* p = (char*)d_ws;
  float*    x    = (float*)p;     p += (size_t)TT * DM * 4;        // residual stream, f32
  uint16_t* qkv  = (uint16_t*)p;  p += (size_t)TT * 192 * 2;       // [t][q|k|v] bf16
  uint16_t* ctx  = (uint16_t*)p;  p += (size_t)TT * DM * 2;
  uint16_t* y    = (uint16_t*)p;  p += (size_t)TT * DM * 2;
  uint16_t* hid  = (uint16_t*)p;  p += (size_t)TT * DFF * 2;
  uint2*    bias = (uint2*)p;     p += (size_t)BB * LL * LL * 8;   // [b][kk][row][h] bf16x4
  float* wtq = (float*)p;  p += (size_t)NL * 64 * 64 * 4;
  float* wtk = (float*)p;  p += (size_t)NL * 64 * 64 * 4;
  float* wtv = (float*)p;  p += (size_t)NL * 64 * 64 * 4;
  float* wto = (float*)p;  p += (size_t)NL * 64 * 64 * 4;
  float* wt1 = (float*)p;  p += (size_t)NL * 64 * 512 * 4;
  float* wt2 = (float*)p;  p += (size_t)NL * 512 * 64 * 4;
  (void)ws_size; (void)in_sizes; (void)n_in; (void)out_size;

  // ---- setup ----
  k_embed<<<TT * DM / 256, 256, 0, stream>>>(enc, deg, semb, demb, x);
  k_trans<<<NL * 64 * 64 / 256, 256, 0, stream>>>(Wq, wtq, 64, 64, 4096);
  k_trans<<<NL * 64 * 64 / 256, 256, 0, stream>>>(Wk, wtk, 64, 64, 4096);
  k_trans<<<NL * 64 * 64 / 256, 256, 0, stream>>>(Wv, wtv, 64, 64, 4096);
  k_trans<<<NL * 64 * 64 / 256, 256, 0, stream>>>(Wo, wto, 64, 64, 4096);
  k_trans<<<NL * 64 * 512 / 256, 256, 0, stream>>>(W1, wt1, 64, 512, 32768);
  k_trans<<<NL * 512 * 64 / 256, 256, 0, stream>>>(W2, wt2, 512, 64, 32768);
  k_bias<<<BB * LL * LL / 256, 256, 0, stream>>>(MD, memb, enc, bias);

  // ---- layers ----
  for (int i = 0; i < NL; ++i) {
    k_qkv <<<dim3(TT / 256, 3), 256, 0, stream>>>(x, wtq + i * 4096, wtk + i * 4096, wtv + i * 4096, qkv);
    k_attn<<<BB * NH * 2 / 4, 256, 0, stream>>>(qkv, (const uint16_t*)bias, ctx);
    k_oproj<<<dim3(TT / 256, 4), 256, 0, stream>>>(ctx, wto + i * 4096, y);
    k_addln<<<TT / 4, 256, 0, stream>>>(y, x);
    k_ffn1<<<dim3(TT / 256, 4), 256, 0, stream>>>(x, wt1 + i * 32768, hid);
    k_ffn2<<<dim3(TT / 256, 4), 256, 0, stream>>>(hid, wt2 + i * 32768, y);
    k_addln<<<TT / 4, 256, 0, stream>>>(y, x);
  }
  k_out<<<TT * DM / 256, 256, 0, stream>>>(x, (float*)d_out);
}

// Round 4
// 691.898 us; speedup vs baseline: 3.6049x; 3.6049x over previous
//
#include <hip/hip_runtime.h>
#include <hip/hip_bf16.h>
#include <stdint.h>

#define DI __device__ __forceinline__

namespace {

constexpr int BB  = 256;   // batch
constexpr int LL  = 128;   // seq len
constexpr int DM  = 64;    // d_model
constexpr int NH  = 4;     // heads
constexpr int DFF = 512;   // ffn dim
constexpr int NL  = 6;     // layers
constexpr int TT  = BB * LL;  // 32768 tokens

typedef __attribute__((ext_vector_type(8))) short bf16x8;   // MFMA A/B frag (4 VGPR)
typedef __attribute__((ext_vector_type(4))) float f32x4;    // MFMA C/D frag

// ---------- bf16 helpers ----------
DI float blo(uint32_t u) { union { uint32_t i; float f; } w; w.i = u << 16; return w.f; }
DI float bhi(uint32_t u) { union { uint32_t i; float f; } w; w.i = u & 0xffff0000u; return w.f; }
DI float bf2f(uint16_t u) { union { uint32_t i; float f; } w; w.i = (uint32_t)u << 16; return w.f; }
DI uint16_t f2bf(float f) {
  union { float f; uint32_t i; } w; w.f = f;
  uint32_t r = (w.i + 0x7fffu + ((w.i >> 16) & 1u)) >> 16;  // RNE
  return (uint16_t)r;
}
DI uint32_t pack2(float a, float b) { return (uint32_t)f2bf(a) | ((uint32_t)f2bf(b) << 16); }

// fragment load: lane l reads 8 bf16 at row (l&15), k-offset (l>>4)*8 of a row-major [16 x ld] tile
DI bf16x8 fragld(const uint16_t* __restrict__ base, int ld, int lane) {
  return *(const bf16x8*)(base + (size_t)(lane & 15) * ld + (lane >> 4) * 8);
}

// ---------- setup kernels ----------
// x[t][d] = src_emb[enc[t]][d] + deg_emb[deg[t]][d] + pe[l][d]; also bf16 shadow xb
__global__ void __launch_bounds__(256) k_embed(const int* __restrict__ enc, const int* __restrict__ deg,
    const float* __restrict__ semb, const float* __restrict__ demb,
    float* __restrict__ x, uint16_t* __restrict__ xb) {
  int idx = blockIdx.x * 256 + threadIdx.x;   // T*64
  int t = idx >> 6, d = idx & 63;
  int l = t & (LL - 1);
  float e = (float)(d & ~1) * -0.14391156831212787f;   // -ln(10000)/64
  float ang = (float)l * __expf(e);
  float pe = (d & 1) ? __cosf(ang) : __sinf(ang);
  float v = semb[enc[t] * DM + d] + demb[deg[t] * DM + d] + pe;
  x[idx] = v;
  xb[idx] = f2bf(v);
}

// wt[mat][colOff + c][k] = bf16(w[mat][k][c])  (transpose + bf16, [N x K] per matrix)
__global__ void __launch_bounds__(256) k_trans(const float* __restrict__ w, uint16_t* __restrict__ wt,
    int K, int O, int dstStride, int colOff) {
  int idx = blockIdx.x * 256 + threadIdx.x;   // nmat*K*O
  int KO = K * O;
  int mat = idx / KO;
  int rem = idx - mat * KO;
  int c = rem / K;
  int k = rem - c * K;
  wt[(size_t)mat * dstStride + (size_t)(colOff + c) * K + k] = f2bf(w[((size_t)mat * K + k) * O + c]);
}

// bias[b][kk][row][h] (bf16 x4 = uint2) = mask ? -1e9 : md_emb[MD[b,row,kk]][h]
__global__ void __launch_bounds__(256) k_bias(const int* __restrict__ MD, const float* __restrict__ memb,
    const int* __restrict__ enc, uint2* __restrict__ bias) {
  int o = blockIdx.x * 256 + threadIdx.x;   // enumerates (b, kk, row)
  int b   = o >> 14;
  int kk  = (o >> 7) & (LL - 1);
  int row = o & (LL - 1);
  uint2 e;
  if (enc[b * LL + kk] == 0) {
    e.x = 0xce6ece6eu; e.y = 0xce6ece6eu;   // bf16(-1e9) packed x4
  } else {
    int v = MD[(b * LL + row) * LL + kk];
    float4 m = *(const float4*)(memb + v * 4);
    e.x = pack2(m.x, m.y); e.y = pack2(m.z, m.w);
  }
  bias[o] = e;
}

// ---------- MFMA GEMM, K=64, weights resident in VGPRs ----------
// A [M x 64] bf16, W [N x 64] bf16 (pre-transposed cols), out bf16 [M x outStride].
// Wave holds NCT col-tiles (NCT*16 cols) x 2 k-chunks of B; streams MT m-tiles of 16 rows.
// grid.y selects the col group of NCT*16 cols.
template<int NCT, int MT, bool RELU>
__global__ void __launch_bounds__(256) k_gemm64(const uint16_t* __restrict__ A,
    const uint16_t* __restrict__ W, uint16_t* __restrict__ out, int outStride, int outColOff) {
  int lane = threadIdx.x & 63;
  int wid = blockIdx.x * 4 + (threadIdx.x >> 6);
  int cgrp = blockIdx.y * (NCT * 16);

  bf16x8 b[NCT][2];
#pragma unroll
  for (int ct = 0; ct < NCT; ++ct)
#pragma unroll
    for (int kc = 0; kc < 2; ++kc)
      b[ct][kc] = fragld(W + (size_t)(cgrp + ct * 16) * 64 + kc * 32, 64, lane);

#pragma unroll
  for (int mt = 0; mt < MT; ++mt) {
    int r0 = (wid * MT + mt) * 16;
    bf16x8 a0 = fragld(A + (size_t)r0 * 64,      64, lane);
    bf16x8 a1 = fragld(A + (size_t)r0 * 64 + 32, 64, lane);
    int orow = r0 + (lane >> 4) * 4;
#pragma unroll
    for (int ct = 0; ct < NCT; ++ct) {
      f32x4 acc = {0.f, 0.f, 0.f, 0.f};
      acc = __builtin_amdgcn_mfma_f32_16x16x32_bf16(a0, b[ct][0], acc, 0, 0, 0);
      acc = __builtin_amdgcn_mfma_f32_16x16x32_bf16(a1, b[ct][1], acc, 0, 0, 0);
      int ocol = outColOff + cgrp + ct * 16 + (lane & 15);
#pragma unroll
      for (int j = 0; j < 4; ++j) {
        float v = RELU ? fmaxf(acc[j], 0.f) : acc[j];
        out[(size_t)(orow + j) * outStride + ocol] = f2bf(v);
      }
    }
  }
}

// ---------- MFMA GEMM, K=512 -> N=64 (FFN2): acc resident, stream k ----------
__global__ void __launch_bounds__(256) k_ffn2m(const uint16_t* __restrict__ A,
    const uint16_t* __restrict__ W, uint16_t* __restrict__ out) {
  int lane = threadIdx.x & 63;
  int wid = blockIdx.x * 4 + (threadIdx.x >> 6);
  int r0 = wid * 16;
  f32x4 acc[4] = {{0,0,0,0},{0,0,0,0},{0,0,0,0},{0,0,0,0}};
#pragma unroll
  for (int kc = 0; kc < 16; ++kc) {
    bf16x8 a = fragld(A + (size_t)r0 * 512 + kc * 32, 512, lane);
#pragma unroll
    for (int ct = 0; ct < 4; ++ct) {
      bf16x8 b = fragld(W + (size_t)(ct * 16) * 512 + kc * 32, 512, lane);
      acc[ct] = __builtin_amdgcn_mfma_f32_16x16x32_bf16(a, b, acc[ct], 0, 0, 0);
    }
  }
  int orow = r0 + (lane >> 4) * 4;
#pragma unroll
  for (int ct = 0; ct < 4; ++ct) {
    int ocol = ct * 16 + (lane & 15);
#pragma unroll
    for (int j = 0; j < 4; ++j)
      out[(size_t)(orow + j) * 64 + ocol] = f2bf(acc[ct][j]);
  }
}

// ---------- fused attention (unchanged from round 3) ----------
__global__ void __launch_bounds__(256) k_attn(const uint16_t* __restrict__ qkv,
    const uint16_t* __restrict__ bias, uint16_t* __restrict__ ctx) {
  int wv = blockIdx.x * 4 + (threadIdx.x >> 6);   // 0..2047
  int lane = threadIdx.x & 63;
  int b = wv >> 3;
  int h = (wv >> 1) & 3;
  int row = (wv & 1) * 64 + lane;
  int t = b * LL + row;

  float q[16];
  {
    const uint16_t* qp = qkv + (size_t)t * 192 + h * 16;
    uint4 a = *(const uint4*)qp;
    uint4 c = *(const uint4*)(qp + 8);
    q[0]=blo(a.x); q[1]=bhi(a.x); q[2]=blo(a.y); q[3]=bhi(a.y);
    q[4]=blo(a.z); q[5]=bhi(a.z); q[6]=blo(a.w); q[7]=bhi(a.w);
    q[8]=blo(c.x); q[9]=bhi(c.x); q[10]=blo(c.y); q[11]=bhi(c.y);
    q[12]=blo(c.z); q[13]=bhi(c.z); q[14]=blo(c.w); q[15]=bhi(c.w);
#pragma unroll
    for (int j = 0; j < 16; ++j) q[j] *= 0.25f;    // 1/sqrt(16)
  }
  float acc[16];
#pragma unroll
  for (int j = 0; j < 16; ++j) acc[j] = 0.f;
  float sum = 0.f;

  const uint16_t* kbase = qkv + (size_t)b * LL * 192 + 64 + h * 16;   // K rows (wave-uniform)
  const uint16_t* vbase = kbase + 64;                                  // V rows
  const uint16_t* bb = bias + ((size_t)b * LL * LL + row) * 4 + h;

#pragma unroll 2
  for (int kk = 0; kk < LL; ++kk) {
    const uint4* kr = (const uint4*)(kbase + kk * 192);
    uint4 ka = kr[0], kb2 = kr[1];
    float d0 = 0.f, d1 = 0.f, d2 = 0.f, d3 = 0.f;
    d0 = fmaf(q[0],  blo(ka.x),  d0);  d1 = fmaf(q[1],  bhi(ka.x),  d1);
    d2 = fmaf(q[2],  blo(ka.y),  d2);  d3 = fmaf(q[3],  bhi(ka.y),  d3);
    d0 = fmaf(q[4],  blo(ka.z),  d0);  d1 = fmaf(q[5],  bhi(ka.z),  d1);
    d2 = fmaf(q[6],  blo(ka.w),  d2);  d3 = fmaf(q[7],  bhi(ka.w),  d3);
    d0 = fmaf(q[8],  blo(kb2.x), d0);  d1 = fmaf(q[9],  bhi(kb2.x), d1);
    d2 = fmaf(q[10], blo(kb2.y), d2);  d3 = fmaf(q[11], bhi(kb2.y), d3);
    d0 = fmaf(q[12], blo(kb2.z), d0);  d1 = fmaf(q[13], bhi(kb2.z), d1);
    d2 = fmaf(q[14], blo(kb2.w), d2);  d3 = fmaf(q[15], bhi(kb2.w), d3);
    float s = ((d0 + d1) + (d2 + d3)) + bf2f(bb[(size_t)kk * 512]);
    float p = __expf(s);
    sum += p;
    const uint4* vr = (const uint4*)(vbase + kk * 192);
    uint4 va = vr[0], vb = vr[1];
    acc[0]  = fmaf(p, blo(va.x), acc[0]);   acc[1]  = fmaf(p, bhi(va.x), acc[1]);
    acc[2]  = fmaf(p, blo(va.y), acc[2]);   acc[3]  = fmaf(p, bhi(va.y), acc[3]);
    acc[4]  = fmaf(p, blo(va.z), acc[4]);   acc[5]  = fmaf(p, bhi(va.z), acc[5]);
    acc[6]  = fmaf(p, blo(va.w), acc[6]);   acc[7]  = fmaf(p, bhi(va.w), acc[7]);
    acc[8]  = fmaf(p, blo(vb.x), acc[8]);   acc[9]  = fmaf(p, bhi(vb.x), acc[9]);
    acc[10] = fmaf(p, blo(vb.y), acc[10]);  acc[11] = fmaf(p, bhi(vb.y), acc[11]);
    acc[12] = fmaf(p, blo(vb.z), acc[12]);  acc[13] = fmaf(p, bhi(vb.z), acc[13]);
    acc[14] = fmaf(p, blo(vb.w), acc[14]);  acc[15] = fmaf(p, bhi(vb.w), acc[15]);
  }
  float inv = 1.0f / sum;
  uint16_t* o = ctx + (size_t)t * DM + h * 16;
  uint4 o0, o1;
  o0.x = pack2(acc[0]*inv,  acc[1]*inv);   o0.y = pack2(acc[2]*inv,  acc[3]*inv);
  o0.z = pack2(acc[4]*inv,  acc[5]*inv);   o0.w = pack2(acc[6]*inv,  acc[7]*inv);
  o1.x = pack2(acc[8]*inv,  acc[9]*inv);   o1.y = pack2(acc[10]*inv, acc[11]*inv);
  o1.z = pack2(acc[12]*inv, acc[13]*inv);  o1.w = pack2(acc[14]*inv, acc[15]*inv);
  *(uint4*)o = o0;
  *(uint4*)(o + 8) = o1;
}

// x[t][:] = LN(bf16(y[t][:]) + x[t][:]); also write bf16 shadow xb. wave per token, lane = d
__global__ void __launch_bounds__(256) k_addln(const uint16_t* __restrict__ y,
    float* __restrict__ x, uint16_t* __restrict__ xb) {
  int wv = blockIdx.x * 4 + (threadIdx.x >> 6);
  int lane = threadIdx.x & 63;
  int i = wv * 64 + lane;
  float v = bf2f(y[i]) + x[i];
  float s = v;
#pragma unroll
  for (int off = 32; off > 0; off >>= 1) s += __shfl_xor(s, off, 64);
  float mu = s * 0.015625f;
  float d = v - mu;
  float s2 = d * d;
#pragma unroll
  for (int off = 32; off > 0; off >>= 1) s2 += __shfl_xor(s2, off, 64);
  float r = d * rsqrtf(s2 * 0.015625f + 1e-5f);
  x[i] = r;
  xb[i] = f2bf(r);
}

// d_out is FLOAT32 (reference output dtype)
__global__ void __launch_bounds__(256) k_out(const float* __restrict__ x, float* __restrict__ out) {
  int i = blockIdx.x * 256 + threadIdx.x;
  out[i] = x[i];
}

} // namespace

extern "C" void kernel_launch(void* const* d_in, const int* in_sizes, int n_in,
                              void* d_out, int out_size, void* d_ws, size_t ws_size,
                              hipStream_t stream) {
  const int* enc = (const int*)d_in[0];
  const int* deg = (const int*)d_in[1];
  const int* MD  = (const int*)d_in[2];
  const float* semb = (const float*)d_in[3];
  const float* demb = (const float*)d_in[4];
  const float* memb = (const float*)d_in[5];
  const float* Wq = (const float*)d_in[6];
  const float* Wk = (const float*)d_in[7];
  const float* Wv = (const float*)d_in[8];
  const float* Wo = (const float*)d_in[9];
  const float* W1 = (const float*)d_in[10];
  const float* W2 = (const float*)d_in[11];

  // ---- workspace layout (~99 MB) ----
  char* p = (char*)d_ws;
  float*    x    = (float*)p;     p += (size_t)TT * DM * 4;        // residual stream, f32
  uint16_t* xb   = (uint16_t*)p;  p += (size_t)TT * DM * 2;        // bf16 shadow of x
  uint16_t* qkv  = (uint16_t*)p;  p += (size_t)TT * 192 * 2;       // [t][q|k|v] bf16
  uint16_t* ctx  = (uint16_t*)p;  p += (size_t)TT * DM * 2;
  uint16_t* y    = (uint16_t*)p;  p += (size_t)TT * DM * 2;
  uint16_t* hid  = (uint16_t*)p;  p += (size_t)TT * DFF * 2;
  uint2*    bias = (uint2*)p;     p += (size_t)BB * LL * LL * 8;   // [b][kk][row][h] bf16x4
  uint16_t* wtqkv = (uint16_t*)p; p += (size_t)NL * 192 * 64 * 2;  // [l][c:192][k:64]
  uint16_t* wto   = (uint16_t*)p; p += (size_t)NL * 64 * 64 * 2;   // [l][c:64][k:64]
  uint16_t* wt1   = (uint16_t*)p; p += (size_t)NL * 512 * 64 * 2;  // [l][c:512][k:64]
  uint16_t* wt2   = (uint16_t*)p; p += (size_t)NL * 64 * 512 * 2;  // [l][c:64][k:512]
  (void)ws_size; (void)in_sizes; (void)n_in; (void)out_size;

  // ---- setup ----
  k_embed<<<TT * DM / 256, 256, 0, stream>>>(enc, deg, semb, demb, x, xb);
  k_trans<<<NL * 64 * 64 / 256, 256, 0, stream>>>(Wq, wtqkv, 64, 64, 192 * 64, 0);
  k_trans<<<NL * 64 * 64 / 256, 256, 0, stream>>>(Wk, wtqkv, 64, 64, 192 * 64, 64);
  k_trans<<<NL * 64 * 64 / 256, 256, 0, stream>>>(Wv, wtqkv, 64, 64, 192 * 64, 128);
  k_trans<<<NL * 64 * 64 / 256, 256, 0, stream>>>(Wo, wto, 64, 64, 64 * 64, 0);
  k_trans<<<NL * 64 * 512 / 256, 256, 0, stream>>>(W1, wt1, 64, 512, 512 * 64, 0);
  k_trans<<<NL * 512 * 64 / 256, 256, 0, stream>>>(W2, wt2, 512, 64, 64 * 512, 0);
  k_bias<<<BB * LL * LL / 256, 256, 0, stream>>>(MD, memb, enc, bias);

  // ---- layers ----
  for (int i = 0; i < NL; ++i) {
    // QKV: [32768x64] @ [64x192] -> qkv   (grid: 2048 waves x 3 col groups)
    k_gemm64<4, 1, false><<<dim3(512, 3), 256, 0, stream>>>(xb, wtqkv + (size_t)i * 192 * 64, qkv, 192, 0);
    k_attn<<<BB * NH * 2 / 4, 256, 0, stream>>>(qkv, (const uint16_t*)bias, ctx);
    // O-proj: [32768x64] @ [64x64] -> y
    k_gemm64<4, 1, false><<<dim3(512, 1), 256, 0, stream>>>(ctx, wto + (size_t)i * 64 * 64, y, 64, 0);
    k_addln<<<TT / 4, 256, 0, stream>>>(y, x, xb);
    // FFN1: [32768x64] @ [64x512] -> relu -> hid   (grid: 1024 waves x 8 col groups, 2 m-tiles/wave)
    k_gemm64<4, 2, true><<<dim3(256, 8), 256, 0, stream>>>(xb, wt1 + (size_t)i * 512 * 64, hid, 512, 0);
    // FFN2: [32768x512] @ [512x64] -> y
    k_ffn2m<<<512, 256, 0, stream>>>(hid, wt2 + (size_t)i * 64 * 512, y);
    k_addln<<<TT / 4, 256, 0, stream>>>(y, x, xb);
  }
  k_out<<<TT * DM / 256, 256, 0, stream>>>(x, (float*)d_out);
}

// Round 5
// 684.498 us; speedup vs baseline: 3.6438x; 1.0108x over previous
//
#include <hip/hip_runtime.h>
#include <hip/hip_bf16.h>
#include <stdint.h>

#define DI __device__ __forceinline__

namespace {

constexpr int BB  = 256;   // batch
constexpr int LL  = 128;   // seq len
constexpr int DM  = 64;    // d_model
constexpr int DFF = 512;   // ffn dim
constexpr int NL  = 6;     // layers
constexpr int TT  = BB * LL;  // 32768 tokens

typedef __attribute__((ext_vector_type(8))) short bf16x8;   // MFMA A/B frag (4 VGPR)
typedef __attribute__((ext_vector_type(4))) float f32x4;    // MFMA C/D frag

// ---------- bf16 helpers ----------
DI float bf2f(uint16_t u) { union { uint32_t i; float f; } w; w.i = (uint32_t)u << 16; return w.f; }
DI uint16_t f2bf(float f) {
  union { float f; uint32_t i; } w; w.f = f;
  uint32_t r = (w.i + 0x7fffu + ((w.i >> 16) & 1u)) >> 16;  // RNE
  return (uint16_t)r;
}
DI uint32_t pack2(float a, float b) { return (uint32_t)f2bf(a) | ((uint32_t)f2bf(b) << 16); }

// fragment load: lane l reads 8 bf16 at row (l&15), k-offset (l>>4)*8 of a row-major [16 x ld] tile
DI bf16x8 fragld(const uint16_t* __restrict__ base, int ld, int lane) {
  return *(const bf16x8*)(base + (size_t)(lane & 15) * ld + (lane >> 4) * 8);
}

// ---------- setup kernels ----------
__global__ void __launch_bounds__(256) k_zero(uint4* __restrict__ p) {
  p[blockIdx.x * 256 + threadIdx.x] = uint4{0, 0, 0, 0};
}

// x[t][d] = src_emb[enc[t]][d] + deg_emb[deg[t]][d] + pe[l][d]; also bf16 shadow xb
__global__ void __launch_bounds__(256) k_embed(const int* __restrict__ enc, const int* __restrict__ deg,
    const float* __restrict__ semb, const float* __restrict__ demb,
    float* __restrict__ x, uint16_t* __restrict__ xb) {
  int idx = blockIdx.x * 256 + threadIdx.x;   // T*64
  int t = idx >> 6, d = idx & 63;
  int l = t & (LL - 1);
  float e = (float)(d & ~1) * -0.14391156831212787f;   // -ln(10000)/64
  float ang = (float)l * __expf(e);
  float pe = (d & 1) ? __cosf(ang) : __sinf(ang);
  float v = semb[enc[t] * DM + d] + demb[deg[t] * DM + d] + pe;
  x[idx] = v;
  xb[idx] = f2bf(v);
}

// wt[mat][colOff + c][k] = bf16(w[mat][k][c])  (transpose + bf16, [N x K] per matrix)
__global__ void __launch_bounds__(256) k_trans(const float* __restrict__ w, uint16_t* __restrict__ wt,
    int K, int O, int dstStride, int colOff) {
  int idx = blockIdx.x * 256 + threadIdx.x;   // nmat*K*O
  int KO = K * O;
  int mat = idx / KO;
  int rem = idx - mat * KO;
  int c = rem / K;
  int k = rem - c * K;
  wt[(size_t)mat * dstStride + (size_t)(colOff + c) * K + k] = f2bf(w[((size_t)mat * K + k) * O + c]);
}

// ---------- QKV GEMM with scatter epilogue ----------
// A=xb [TT x 64]; W = wtqkv layer slice [192 x 64]; seg = blockIdx.y (q,k,v)
// q,k -> [bh][128][32] zero-padded; v -> vt [bh][16][128] (transposed)
__global__ void __launch_bounds__(256) k_qkvg(const uint16_t* __restrict__ A,
    const uint16_t* __restrict__ W, uint16_t* __restrict__ qpad,
    uint16_t* __restrict__ kpad, uint16_t* __restrict__ vt) {
  int seg = blockIdx.y;
  const uint16_t* Ws = W + seg * 64 * 64;
  int lane = threadIdx.x & 63;
  int g = lane >> 4, c = lane & 15;
  int wid = blockIdx.x * 4 + (threadIdx.x >> 6);
  int r0 = wid * 16;
  int b = r0 >> 7, rl = r0 & 127;
  bf16x8 a0 = fragld(A + (size_t)r0 * 64, 64, lane);
  bf16x8 a1 = fragld(A + (size_t)r0 * 64 + 32, 64, lane);
#pragma unroll
  for (int ct = 0; ct < 4; ++ct) {   // head = ct, dim = c
    f32x4 acc = {0.f, 0.f, 0.f, 0.f};
    acc = __builtin_amdgcn_mfma_f32_16x16x32_bf16(a0, fragld(Ws + ct * 16 * 64, 64, lane), acc, 0, 0, 0);
    acc = __builtin_amdgcn_mfma_f32_16x16x32_bf16(a1, fragld(Ws + ct * 16 * 64 + 32, 64, lane), acc, 0, 0, 0);
    if (seg == 2) {
      uint16_t* o = vt + ((size_t)(b * 4 + ct) * 16 + c) * 128 + rl + g * 4;
      uint2 pk; pk.x = pack2(acc[0], acc[1]); pk.y = pack2(acc[2], acc[3]);
      *(uint2*)o = pk;
    } else {
      uint16_t* dst = (seg == 0 ? qpad : kpad) + ((size_t)(b * 4 + ct) * 128 + rl + g * 4) * 32 + c;
#pragma unroll
      for (int j = 0; j < 4; ++j) dst[j * 32] = f2bf(acc[j]);
    }
  }
}

// ---------- MFMA fused attention ----------
// workgroup = (b,h) [XCD-grouped by b], 4 waves x 32 rows. No barriers (wave-local LDS).
__global__ void __launch_bounds__(256) k_attn(const uint16_t* __restrict__ qpad,
    const uint16_t* __restrict__ kpad, const uint16_t* __restrict__ vt,
    const int* __restrict__ MD, const float* __restrict__ memb,
    const int* __restrict__ enc, uint16_t* __restrict__ ctx) {
  __shared__ uint16_t plds[4][32 * 128];   // per-wave P tile, XOR-swizzled
  int i = blockIdx.x;
  int b = (i >> 5) * 8 + (i & 7);   // 4 heads of one b land on the same XCD
  int h = (i >> 3) & 3;
  int w = threadIdx.x >> 6;
  int lane = threadIdx.x & 63;
  int g = lane >> 4, c = lane & 15;
  size_t bh = (size_t)b * 4 + h;

  const uint16_t* qb = qpad + (bh * 128 + w * 32) * 32;
  const uint16_t* kb = kpad + bh * 128 * 32;
  const uint16_t* vb = vt + bh * 16 * 128;
  const int* mdb = MD + (size_t)b * LL * LL;

  bf16x8 kf[8];
#pragma unroll
  for (int ct = 0; ct < 8; ++ct) kf[ct] = fragld(kb + ct * 16 * 32, 32, lane);
  bf16x8 vf[4];
#pragma unroll
  for (int kc = 0; kc < 4; ++kc) vf[kc] = fragld(vb + kc * 32, 128, lane);

  bool msk = (enc[b * LL + c] == 0);        // placeholder; real mask per ct below
  (void)msk;
  char* myp = (char*)&plds[w][0];
  float inv_rs[2][4];

#pragma unroll
  for (int rt = 0; rt < 2; ++rt) {
    bf16x8 qf = fragld(qb + rt * 16 * 32, 32, lane);
    f32x4 s[8];
#pragma unroll
    for (int ct = 0; ct < 8; ++ct)
      s[ct] = __builtin_amdgcn_mfma_f32_16x16x32_bf16(qf, kf[ct], (f32x4){0.f, 0.f, 0.f, 0.f}, 0, 0, 0);
    int rbase = w * 32 + rt * 16 + g * 4;   // global row of j=0
    float rs[4] = {0.f, 0.f, 0.f, 0.f};
#pragma unroll
    for (int ct = 0; ct < 8; ++ct) {
      int kk = ct * 16 + c;
      bool masked = (enc[b * LL + kk] == 0);
#pragma unroll
      for (int j = 0; j < 4; ++j) {
        int md = mdb[(rbase + j) * LL + kk];
        float bias = masked ? -1e9f : memb[md * 4 + h];
        float p = __expf(s[ct][j] * 0.25f + bias);
        rs[j] += p;
        int row = rt * 16 + g * 4 + j;      // local row 0..31
        int byteoff = row * 256 + ((kk * 2) ^ ((row & 7) << 4));
        *(uint16_t*)(myp + byteoff) = f2bf(p);
      }
    }
#pragma unroll
    for (int off = 1; off < 16; off <<= 1)
#pragma unroll
      for (int j = 0; j < 4; ++j) rs[j] += __shfl_xor(rs[j], off, 64);
#pragma unroll
    for (int j = 0; j < 4; ++j) inv_rs[rt][j] = 1.0f / rs[j];
  }

  // PV: out[32 x 16] = P[32 x 128] @ V[128 x 16]
#pragma unroll
  for (int rt = 0; rt < 2; ++rt) {
    f32x4 o = {0.f, 0.f, 0.f, 0.f};
#pragma unroll
    for (int kc = 0; kc < 4; ++kc) {
      int row = rt * 16 + c;
      int byteoff = row * 256 + ((kc * 64 + g * 16) ^ ((row & 7) << 4));
      bf16x8 af = *(const bf16x8*)(myp + byteoff);
      o = __builtin_amdgcn_mfma_f32_16x16x32_bf16(af, vf[kc], o, 0, 0, 0);
    }
    int t = b * LL + w * 32 + rt * 16 + g * 4;
#pragma unroll
    for (int j = 0; j < 4; ++j)
      ctx[(size_t)(t + j) * DM + h * 16 + c] = f2bf(o[j] * inv_rs[rt][j]);
  }
}

// ---------- O-proj + residual + LN fused (wave owns 16 rows x all 64 cols) ----------
__global__ void __launch_bounds__(256) k_oproj_ln(const uint16_t* __restrict__ ctxb,
    const uint16_t* __restrict__ W, float* __restrict__ x, uint16_t* __restrict__ xb) {
  int lane = threadIdx.x & 63, g = lane >> 4, c = lane & 15;
  int wid = blockIdx.x * 4 + (threadIdx.x >> 6);
  int r0 = wid * 16;
  bf16x8 a0 = fragld(ctxb + (size_t)r0 * 64, 64, lane);
  bf16x8 a1 = fragld(ctxb + (size_t)r0 * 64 + 32, 64, lane);
  float v[4][4];   // [j][ct]
#pragma unroll
  for (int ct = 0; ct < 4; ++ct) {
    f32x4 acc = {0.f, 0.f, 0.f, 0.f};
    acc = __builtin_amdgcn_mfma_f32_16x16x32_bf16(a0, fragld(W + ct * 16 * 64, 64, lane), acc, 0, 0, 0);
    acc = __builtin_amdgcn_mfma_f32_16x16x32_bf16(a1, fragld(W + ct * 16 * 64 + 32, 64, lane), acc, 0, 0, 0);
#pragma unroll
    for (int j = 0; j < 4; ++j)
      v[j][ct] = acc[j] + x[(size_t)(r0 + g * 4 + j) * 64 + ct * 16 + c];
  }
  float sum[4], sq[4];
#pragma unroll
  for (int j = 0; j < 4; ++j) sum[j] = (v[j][0] + v[j][1]) + (v[j][2] + v[j][3]);
#pragma unroll
  for (int off = 1; off < 16; off <<= 1)
#pragma unroll
    for (int j = 0; j < 4; ++j) sum[j] += __shfl_xor(sum[j], off, 64);
#pragma unroll
  for (int j = 0; j < 4; ++j) {
    float mu = sum[j] * 0.015625f;
#pragma unroll
    for (int ct = 0; ct < 4; ++ct) v[j][ct] -= mu;
    sq[j] = (v[j][0] * v[j][0] + v[j][1] * v[j][1]) + (v[j][2] * v[j][2] + v[j][3] * v[j][3]);
  }
#pragma unroll
  for (int off = 1; off < 16; off <<= 1)
#pragma unroll
    for (int j = 0; j < 4; ++j) sq[j] += __shfl_xor(sq[j], off, 64);
#pragma unroll
  for (int j = 0; j < 4; ++j) {
    float rstd = rsqrtf(sq[j] * 0.015625f + 1e-5f);
#pragma unroll
    for (int ct = 0; ct < 4; ++ct) {
      float r = v[j][ct] * rstd;
      size_t idx = (size_t)(r0 + g * 4 + j) * 64 + ct * 16 + c;
      x[idx] = r;
      xb[idx] = f2bf(r);
    }
  }
}

// ---------- FFN1 (K=64, weights in VGPR), relu ----------
template<int NCT, int MT, bool RELU>
__global__ void __launch_bounds__(256) k_gemm64(const uint16_t* __restrict__ A,
    const uint16_t* __restrict__ W, uint16_t* __restrict__ out, int outStride, int outColOff) {
  int lane = threadIdx.x & 63;
  int wid = blockIdx.x * 4 + (threadIdx.x >> 6);
  int cgrp = blockIdx.y * (NCT * 16);
  bf16x8 b[NCT][2];
#pragma unroll
  for (int ct = 0; ct < NCT; ++ct)
#pragma unroll
    for (int kc = 0; kc < 2; ++kc)
      b[ct][kc] = fragld(W + (size_t)(cgrp + ct * 16) * 64 + kc * 32, 64, lane);
#pragma unroll
  for (int mt = 0; mt < MT; ++mt) {
    int r0 = (wid * MT + mt) * 16;
    bf16x8 a0 = fragld(A + (size_t)r0 * 64,      64, lane);
    bf16x8 a1 = fragld(A + (size_t)r0 * 64 + 32, 64, lane);
    int orow = r0 + (lane >> 4) * 4;
#pragma unroll
    for (int ct = 0; ct < NCT; ++ct) {
      f32x4 acc = {0.f, 0.f, 0.f, 0.f};
      acc = __builtin_amdgcn_mfma_f32_16x16x32_bf16(a0, b[ct][0], acc, 0, 0, 0);
      acc = __builtin_amdgcn_mfma_f32_16x16x32_bf16(a1, b[ct][1], acc, 0, 0, 0);
      int ocol = outColOff + cgrp + ct * 16 + (lane & 15);
#pragma unroll
      for (int j = 0; j < 4; ++j) {
        float v = RELU ? fmaxf(acc[j], 0.f) : acc[j];
        out[(size_t)(orow + j) * outStride + ocol] = f2bf(v);
      }
    }
  }
}

// ---------- FFN2 (K=512) + residual + LN fused ----------
__global__ void __launch_bounds__(256) k_ffn2_ln(const uint16_t* __restrict__ hid,
    const uint16_t* __restrict__ W, float* __restrict__ x, uint16_t* __restrict__ xb) {
  int lane = threadIdx.x & 63, g = lane >> 4, c = lane & 15;
  int wid = blockIdx.x * 4 + (threadIdx.x >> 6);
  int r0 = wid * 16;
  f32x4 acc[4] = {{0,0,0,0},{0,0,0,0},{0,0,0,0},{0,0,0,0}};
#pragma unroll
  for (int kc = 0; kc < 16; ++kc) {
    bf16x8 a = fragld(hid + (size_t)r0 * 512 + kc * 32, 512, lane);
#pragma unroll
    for (int ct = 0; ct < 4; ++ct)
      acc[ct] = __builtin_amdgcn_mfma_f32_16x16x32_bf16(a, fragld(W + (size_t)(ct * 16) * 512 + kc * 32, 512, lane), acc[ct], 0, 0, 0);
  }
  float v[4][4];
#pragma unroll
  for (int ct = 0; ct < 4; ++ct)
#pragma unroll
    for (int j = 0; j < 4; ++j)
      v[j][ct] = acc[ct][j] + x[(size_t)(r0 + g * 4 + j) * 64 + ct * 16 + c];
  float sum[4], sq[4];
#pragma unroll
  for (int j = 0; j < 4; ++j) sum[j] = (v[j][0] + v[j][1]) + (v[j][2] + v[j][3]);
#pragma unroll
  for (int off = 1; off < 16; off <<= 1)
#pragma unroll
    for (int j = 0; j < 4; ++j) sum[j] += __shfl_xor(sum[j], off, 64);
#pragma unroll
  for (int j = 0; j < 4; ++j) {
    float mu = sum[j] * 0.015625f;
#pragma unroll
    for (int ct = 0; ct < 4; ++ct) v[j][ct] -= mu;
    sq[j] = (v[j][0] * v[j][0] + v[j][1] * v[j][1]) + (v[j][2] * v[j][2] + v[j][3] * v[j][3]);
  }
#pragma unroll
  for (int off = 1; off < 16; off <<= 1)
#pragma unroll
    for (int j = 0; j < 4; ++j) sq[j] += __shfl_xor(sq[j], off, 64);
#pragma unroll
  for (int j = 0; j < 4; ++j) {
    float rstd = rsqrtf(sq[j] * 0.015625f + 1e-5f);
#pragma unroll
    for (int ct = 0; ct < 4; ++ct) {
      float r = v[j][ct] * rstd;
      size_t idx = (size_t)(r0 + g * 4 + j) * 64 + ct * 16 + c;
      x[idx] = r;
      xb[idx] = f2bf(r);
    }
  }
}

// d_out is FLOAT32 (reference output dtype)
__global__ void __launch_bounds__(256) k_out(const float* __restrict__ x, float* __restrict__ out) {
  int i = blockIdx.x * 256 + threadIdx.x;
  out[i] = x[i];
}

} // namespace

extern "C" void kernel_launch(void* const* d_in, const int* in_sizes, int n_in,
                              void* d_out, int out_size, void* d_ws, size_t ws_size,
                              hipStream_t stream) {
  const int* enc = (const int*)d_in[0];
  const int* deg = (const int*)d_in[1];
  const int* MD  = (const int*)d_in[2];
  const float* semb = (const float*)d_in[3];
  const float* demb = (const float*)d_in[4];
  const float* memb = (const float*)d_in[5];
  const float* Wq = (const float*)d_in[6];
  const float* Wk = (const float*)d_in[7];
  const float* Wv = (const float*)d_in[8];
  const float* Wo = (const float*)d_in[9];
  const float* W1 = (const float*)d_in[10];
  const float* W2 = (const float*)d_in[11];

  // ---- workspace layout (~74 MB) ----
  char* p = (char*)d_ws;
  float*    x    = (float*)p;     p += (size_t)TT * DM * 4;        // residual stream, f32
  uint16_t* xb   = (uint16_t*)p;  p += (size_t)TT * DM * 2;        // bf16 shadow of x
  uint16_t* qpad = (uint16_t*)p;  p += (size_t)BB * 4 * 128 * 32 * 2;  // [bh][128][32] (pad zeroed)
  uint16_t* kpad = (uint16_t*)p;  p += (size_t)BB * 4 * 128 * 32 * 2;
  uint16_t* vt   = (uint16_t*)p;  p += (size_t)BB * 4 * 16 * 128 * 2;  // [bh][16][128] = V^T
  uint16_t* ctx  = (uint16_t*)p;  p += (size_t)TT * DM * 2;
  uint16_t* hid  = (uint16_t*)p;  p += (size_t)TT * DFF * 2;
  uint16_t* wtqkv = (uint16_t*)p; p += (size_t)NL * 192 * 64 * 2;  // [l][c:192][k:64]
  uint16_t* wto   = (uint16_t*)p; p += (size_t)NL * 64 * 64 * 2;   // [l][c:64][k:64]
  uint16_t* wt1   = (uint16_t*)p; p += (size_t)NL * 512 * 64 * 2;  // [l][c:512][k:64]
  uint16_t* wt2   = (uint16_t*)p; p += (size_t)NL * 64 * 512 * 2;  // [l][c:64][k:512]
  (void)ws_size; (void)in_sizes; (void)n_in; (void)out_size;

  // ---- setup ----
  // zero qpad+kpad (16 MB contiguous) so pad cols 16..31 are 0 every call
  k_zero<<<(int)(((size_t)BB * 4 * 128 * 32 * 2 * 2) / 16 / 256), 256, 0, stream>>>((uint4*)qpad);
  k_embed<<<TT * DM / 256, 256, 0, stream>>>(enc, deg, semb, demb, x, xb);
  k_trans<<<NL * 64 * 64 / 256, 256, 0, stream>>>(Wq, wtqkv, 64, 64, 192 * 64, 0);
  k_trans<<<NL * 64 * 64 / 256, 256, 0, stream>>>(Wk, wtqkv, 64, 64, 192 * 64, 64);
  k_trans<<<NL * 64 * 64 / 256, 256, 0, stream>>>(Wv, wtqkv, 64, 64, 192 * 64, 128);
  k_trans<<<NL * 64 * 64 / 256, 256, 0, stream>>>(Wo, wto, 64, 64, 64 * 64, 0);
  k_trans<<<NL * 64 * 512 / 256, 256, 0, stream>>>(W1, wt1, 64, 512, 512 * 64, 0);
  k_trans<<<NL * 512 * 64 / 256, 256, 0, stream>>>(W2, wt2, 512, 64, 64 * 512, 0);

  // ---- layers ----
  for (int i = 0; i < NL; ++i) {
    k_qkvg<<<dim3(TT / 16 / 4, 3), 256, 0, stream>>>(xb, wtqkv + (size_t)i * 192 * 64, qpad, kpad, vt);
    k_attn<<<BB * 4, 256, 0, stream>>>(qpad, kpad, vt, MD, memb, enc, ctx);
    k_oproj_ln<<<TT / 16 / 4, 256, 0, stream>>>(ctx, wto + (size_t)i * 64 * 64, x, xb);
    k_gemm64<4, 2, true><<<dim3(TT / 32 / 4, 8), 256, 0, stream>>>(xb, wt1 + (size_t)i * 512 * 64, hid, 512, 0);
    k_ffn2_ln<<<TT / 16 / 4, 256, 0, stream>>>(hid, wt2 + (size_t)i * 64 * 512, x, xb);
  }
  k_out<<<TT * DM / 256, 256, 0, stream>>>(x, (float*)d_out);
}

// Round 6
// 548.543 us; speedup vs baseline: 4.5469x; 1.2478x over previous
//
#include <hip/hip_runtime.h>
#include <hip/hip_bf16.h>
#include <stdint.h>

#define DI __device__ __forceinline__

namespace {

constexpr int BB  = 256;   // batch
constexpr int LL  = 128;   // seq len
constexpr int DM  = 64;    // d_model
constexpr int DFF = 512;   // ffn dim
constexpr int NL  = 6;     // layers
constexpr int TT  = BB * LL;  // 32768 tokens

typedef __attribute__((ext_vector_type(8))) short bf16x8;   // MFMA A/B frag (4 VGPR)
typedef __attribute__((ext_vector_type(4))) float f32x4;    // MFMA C/D frag

// ---------- bf16 helpers ----------
DI float bf2f(uint16_t u) { union { uint32_t i; float f; } w; w.i = (uint32_t)u << 16; return w.f; }
DI uint16_t f2bf(float f) {
  union { float f; uint32_t i; } w; w.f = f;
  uint32_t r = (w.i + 0x7fffu + ((w.i >> 16) & 1u)) >> 16;  // RNE
  return (uint16_t)r;
}
DI uint32_t pack2(float a, float b) { return (uint32_t)f2bf(a) | ((uint32_t)f2bf(b) << 16); }

// fragment load: lane l reads 8 bf16 at row (l&15), k-offset (l>>4)*8 of a row-major [16 x ld] tile
DI bf16x8 fragld(const uint16_t* __restrict__ base, int ld, int lane) {
  return *(const bf16x8*)(base + (size_t)(lane & 15) * ld + (lane >> 4) * 8);
}

// ---------- setup kernels ----------
__global__ void __launch_bounds__(256) k_zero(uint4* __restrict__ p) {
  p[blockIdx.x * 256 + threadIdx.x] = uint4{0, 0, 0, 0};
}

// x[t][d] = src_emb[enc[t]][d] + deg_emb[deg[t]][d] + pe[l][d]; also bf16 shadow xb
__global__ void __launch_bounds__(256) k_embed(const int* __restrict__ enc, const int* __restrict__ deg,
    const float* __restrict__ semb, const float* __restrict__ demb,
    float* __restrict__ x, uint16_t* __restrict__ xb) {
  int idx = blockIdx.x * 256 + threadIdx.x;   // T*64
  int t = idx >> 6, d = idx & 63;
  int l = t & (LL - 1);
  float e = (float)(d & ~1) * -0.14391156831212787f;   // -ln(10000)/64
  float ang = (float)l * __expf(e);
  float pe = (d & 1) ? __cosf(ang) : __sinf(ang);
  float v = semb[enc[t] * DM + d] + demb[deg[t] * DM + d] + pe;
  x[idx] = v;
  xb[idx] = f2bf(v);
}

// wt[mat][colOff + c][k] = bf16(w[mat][k][c])  (transpose + bf16, [N x K] per matrix)
__global__ void __launch_bounds__(256) k_trans(const float* __restrict__ w, uint16_t* __restrict__ wt,
    int K, int O, int dstStride, int colOff) {
  int idx = blockIdx.x * 256 + threadIdx.x;   // nmat*K*O
  int KO = K * O;
  int mat = idx / KO;
  int rem = idx - mat * KO;
  int c = rem / K;
  int k = rem - c * K;
  wt[(size_t)mat * dstStride + (size_t)(colOff + c) * K + k] = f2bf(w[((size_t)mat * K + k) * O + c]);
}

// biasT[b][h][r][kk] bf16 = mask(kk) ? -1e9 : md_emb[MD[b,r,kk]][h]   (layer-invariant, computed once)
// thread o = (b*128 + r)*128 + kk  ->  MD read is exactly MD[o] (fully coalesced)
__global__ void __launch_bounds__(256) k_bias2(const int* __restrict__ MD, const float* __restrict__ memb,
    const int* __restrict__ enc, uint16_t* __restrict__ biasT) {
  int o = blockIdx.x * 256 + threadIdx.x;   // BB*LL*LL
  int b  = o >> 14;
  int r  = (o >> 7) & (LL - 1);
  int kk = o & (LL - 1);
  bool mask = (enc[b * LL + kk] == 0);
  int md = MD[o];
  float4 m = *(const float4*)(memb + md * 4);
  float mv[4] = {m.x, m.y, m.z, m.w};
#pragma unroll
  for (int h = 0; h < 4; ++h) {
    uint16_t v = mask ? (uint16_t)0xce6eu : f2bf(mv[h]);
    biasT[(((size_t)(b * 4 + h) * LL) + r) * LL + kk] = v;
  }
}

// ---------- QKV GEMM with scatter epilogue ----------
// A=xb [TT x 64]; W = wtqkv layer slice [192 x 64]; seg = blockIdx.y (q,k,v)
// q,k -> [bh][128][32] zero-padded; v -> vt [bh][16][128] (transposed)
__global__ void __launch_bounds__(256) k_qkvg(const uint16_t* __restrict__ A,
    const uint16_t* __restrict__ W, uint16_t* __restrict__ qpad,
    uint16_t* __restrict__ kpad, uint16_t* __restrict__ vt) {
  int seg = blockIdx.y;
  const uint16_t* Ws = W + seg * 64 * 64;
  int lane = threadIdx.x & 63;
  int g = lane >> 4, c = lane & 15;
  int wid = blockIdx.x * 4 + (threadIdx.x >> 6);
  int r0 = wid * 16;
  int b = r0 >> 7, rl = r0 & 127;
  bf16x8 a0 = fragld(A + (size_t)r0 * 64, 64, lane);
  bf16x8 a1 = fragld(A + (size_t)r0 * 64 + 32, 64, lane);
#pragma unroll
  for (int ct = 0; ct < 4; ++ct) {   // head = ct, dim = c
    f32x4 acc = {0.f, 0.f, 0.f, 0.f};
    acc = __builtin_amdgcn_mfma_f32_16x16x32_bf16(a0, fragld(Ws + ct * 16 * 64, 64, lane), acc, 0, 0, 0);
    acc = __builtin_amdgcn_mfma_f32_16x16x32_bf16(a1, fragld(Ws + ct * 16 * 64 + 32, 64, lane), acc, 0, 0, 0);
    if (seg == 2) {
      uint16_t* o = vt + ((size_t)(b * 4 + ct) * 16 + c) * 128 + rl + g * 4;
      uint2 pk; pk.x = pack2(acc[0], acc[1]); pk.y = pack2(acc[2], acc[3]);
      *(uint2*)o = pk;
    } else {
      uint16_t* dst = (seg == 0 ? qpad : kpad) + ((size_t)(b * 4 + ct) * 128 + rl + g * 4) * 32 + c;
#pragma unroll
      for (int j = 0; j < 4; ++j) dst[j * 32] = f2bf(acc[j]);
    }
  }
}

// ---------- MFMA fused attention, precomputed bias plane ----------
// workgroup = (b,h) [XCD-grouped by b], 4 waves x 32 rows. No barriers (wave-local LDS).
__global__ void __launch_bounds__(256) k_attn(const uint16_t* __restrict__ qpad,
    const uint16_t* __restrict__ kpad, const uint16_t* __restrict__ vt,
    const uint16_t* __restrict__ biasT, uint16_t* __restrict__ ctx) {
  __shared__ uint16_t plds[4][32 * 128];   // per-wave P tile, XOR-swizzled
  int i = blockIdx.x;
  int b = (i >> 5) * 8 + (i & 7);   // 4 heads of one b land on the same XCD
  int h = (i >> 3) & 3;
  int w = threadIdx.x >> 6;
  int lane = threadIdx.x & 63;
  int g = lane >> 4, c = lane & 15;
  size_t bh = (size_t)b * 4 + h;

  const uint16_t* qb = qpad + (bh * 128 + w * 32) * 32;
  const uint16_t* kb = kpad + bh * 128 * 32;
  const uint16_t* vb = vt + bh * 16 * 128;
  const uint16_t* bb = biasT + bh * (LL * LL);

  bf16x8 kf[8];
#pragma unroll
  for (int ct = 0; ct < 8; ++ct) kf[ct] = fragld(kb + ct * 16 * 32, 32, lane);
  bf16x8 vf[4];
#pragma unroll
  for (int kc = 0; kc < 4; ++kc) vf[kc] = fragld(vb + kc * 32, 128, lane);

  char* myp = (char*)&plds[w][0];
  float inv_rs[2][4];

#pragma unroll
  for (int rt = 0; rt < 2; ++rt) {
    bf16x8 qf = fragld(qb + rt * 16 * 32, 32, lane);
    f32x4 s[8];
#pragma unroll
    for (int ct = 0; ct < 8; ++ct)
      s[ct] = __builtin_amdgcn_mfma_f32_16x16x32_bf16(qf, kf[ct], (f32x4){0.f, 0.f, 0.f, 0.f}, 0, 0, 0);
    int rbase = w * 32 + rt * 16 + g * 4;   // global row of j=0
    float rs[4] = {0.f, 0.f, 0.f, 0.f};
#pragma unroll
    for (int ct = 0; ct < 8; ++ct) {
      int kk = ct * 16 + c;
#pragma unroll
      for (int j = 0; j < 4; ++j) {
        float bias = bf2f(bb[(size_t)(rbase + j) * LL + kk]);
        float p = __expf(fmaf(s[ct][j], 0.25f, bias));
        rs[j] += p;
        int row = rt * 16 + g * 4 + j;      // local row 0..31
        int byteoff = row * 256 + ((kk * 2) ^ ((row & 7) << 4));
        *(uint16_t*)(myp + byteoff) = f2bf(p);
      }
    }
#pragma unroll
    for (int off = 1; off < 16; off <<= 1)
#pragma unroll
      for (int j = 0; j < 4; ++j) rs[j] += __shfl_xor(rs[j], off, 64);
#pragma unroll
    for (int j = 0; j < 4; ++j) inv_rs[rt][j] = 1.0f / rs[j];
  }

  // PV: out[32 x 16] = P[32 x 128] @ V[128 x 16]
#pragma unroll
  for (int rt = 0; rt < 2; ++rt) {
    f32x4 o = {0.f, 0.f, 0.f, 0.f};
#pragma unroll
    for (int kc = 0; kc < 4; ++kc) {
      int row = rt * 16 + c;
      int byteoff = row * 256 + ((kc * 64 + g * 16) ^ ((row & 7) << 4));
      bf16x8 af = *(const bf16x8*)(myp + byteoff);
      o = __builtin_amdgcn_mfma_f32_16x16x32_bf16(af, vf[kc], o, 0, 0, 0);
    }
    int t = b * LL + w * 32 + rt * 16 + g * 4;
#pragma unroll
    for (int j = 0; j < 4; ++j)
      ctx[(size_t)(t + j) * DM + h * 16 + c] = f2bf(o[j] * inv_rs[rt][j]);
  }
}

// ---------- O-proj + residual + LN fused (wave owns 16 rows x all 64 cols) ----------
__global__ void __launch_bounds__(256) k_oproj_ln(const uint16_t* __restrict__ ctxb,
    const uint16_t* __restrict__ W, float* __restrict__ x, uint16_t* __restrict__ xb) {
  int lane = threadIdx.x & 63, g = lane >> 4, c = lane & 15;
  int wid = blockIdx.x * 4 + (threadIdx.x >> 6);
  int r0 = wid * 16;
  bf16x8 a0 = fragld(ctxb + (size_t)r0 * 64, 64, lane);
  bf16x8 a1 = fragld(ctxb + (size_t)r0 * 64 + 32, 64, lane);
  float v[4][4];   // [j][ct]
#pragma unroll
  for (int ct = 0; ct < 4; ++ct) {
    f32x4 acc = {0.f, 0.f, 0.f, 0.f};
    acc = __builtin_amdgcn_mfma_f32_16x16x32_bf16(a0, fragld(W + ct * 16 * 64, 64, lane), acc, 0, 0, 0);
    acc = __builtin_amdgcn_mfma_f32_16x16x32_bf16(a1, fragld(W + ct * 16 * 64 + 32, 64, lane), acc, 0, 0, 0);
#pragma unroll
    for (int j = 0; j < 4; ++j)
      v[j][ct] = acc[j] + x[(size_t)(r0 + g * 4 + j) * 64 + ct * 16 + c];
  }
  float sum[4], sq[4];
#pragma unroll
  for (int j = 0; j < 4; ++j) sum[j] = (v[j][0] + v[j][1]) + (v[j][2] + v[j][3]);
#pragma unroll
  for (int off = 1; off < 16; off <<= 1)
#pragma unroll
    for (int j = 0; j < 4; ++j) sum[j] += __shfl_xor(sum[j], off, 64);
#pragma unroll
  for (int j = 0; j < 4; ++j) {
    float mu = sum[j] * 0.015625f;
#pragma unroll
    for (int ct = 0; ct < 4; ++ct) v[j][ct] -= mu;
    sq[j] = (v[j][0] * v[j][0] + v[j][1] * v[j][1]) + (v[j][2] * v[j][2] + v[j][3] * v[j][3]);
  }
#pragma unroll
  for (int off = 1; off < 16; off <<= 1)
#pragma unroll
    for (int j = 0; j < 4; ++j) sq[j] += __shfl_xor(sq[j], off, 64);
#pragma unroll
  for (int j = 0; j < 4; ++j) {
    float rstd = rsqrtf(sq[j] * 0.015625f + 1e-5f);
#pragma unroll
    for (int ct = 0; ct < 4; ++ct) {
      float r = v[j][ct] * rstd;
      size_t idx = (size_t)(r0 + g * 4 + j) * 64 + ct * 16 + c;
      x[idx] = r;
      xb[idx] = f2bf(r);
    }
  }
}

// ---------- FFN1 (K=64, weights in VGPR), relu ----------
template<int NCT, int MT, bool RELU>
__global__ void __launch_bounds__(256) k_gemm64(const uint16_t* __restrict__ A,
    const uint16_t* __restrict__ W, uint16_t* __restrict__ out, int outStride, int outColOff) {
  int lane = threadIdx.x & 63;
  int wid = blockIdx.x * 4 + (threadIdx.x >> 6);
  int cgrp = blockIdx.y * (NCT * 16);
  bf16x8 b[NCT][2];
#pragma unroll
  for (int ct = 0; ct < NCT; ++ct)
#pragma unroll
    for (int kc = 0; kc < 2; ++kc)
      b[ct][kc] = fragld(W + (size_t)(cgrp + ct * 16) * 64 + kc * 32, 64, lane);
#pragma unroll
  for (int mt = 0; mt < MT; ++mt) {
    int r0 = (wid * MT + mt) * 16;
    bf16x8 a0 = fragld(A + (size_t)r0 * 64,      64, lane);
    bf16x8 a1 = fragld(A + (size_t)r0 * 64 + 32, 64, lane);
    int orow = r0 + (lane >> 4) * 4;
#pragma unroll
    for (int ct = 0; ct < NCT; ++ct) {
      f32x4 acc = {0.f, 0.f, 0.f, 0.f};
      acc = __builtin_amdgcn_mfma_f32_16x16x32_bf16(a0, b[ct][0], acc, 0, 0, 0);
      acc = __builtin_amdgcn_mfma_f32_16x16x32_bf16(a1, b[ct][1], acc, 0, 0, 0);
      int ocol = outColOff + cgrp + ct * 16 + (lane & 15);
#pragma unroll
      for (int j = 0; j < 4; ++j) {
        float v = RELU ? fmaxf(acc[j], 0.f) : acc[j];
        out[(size_t)(orow + j) * outStride + ocol] = f2bf(v);
      }
    }
  }
}

// ---------- FFN2 (K=512) + residual + LN fused ----------
__global__ void __launch_bounds__(256) k_ffn2_ln(const uint16_t* __restrict__ hid,
    const uint16_t* __restrict__ W, float* __restrict__ x, uint16_t* __restrict__ xb) {
  int lane = threadIdx.x & 63, g = lane >> 4, c = lane & 15;
  int wid = blockIdx.x * 4 + (threadIdx.x >> 6);
  int r0 = wid * 16;
  f32x4 acc[4] = {{0,0,0,0},{0,0,0,0},{0,0,0,0},{0,0,0,0}};
#pragma unroll
  for (int kc = 0; kc < 16; ++kc) {
    bf16x8 a = fragld(hid + (size_t)r0 * 512 + kc * 32, 512, lane);
#pragma unroll
    for (int ct = 0; ct < 4; ++ct)
      acc[ct] = __builtin_amdgcn_mfma_f32_16x16x32_bf16(a, fragld(W + (size_t)(ct * 16) * 512 + kc * 32, 512, lane), acc[ct], 0, 0, 0);
  }
  float v[4][4];
#pragma unroll
  for (int ct = 0; ct < 4; ++ct)
#pragma unroll
    for (int j = 0; j < 4; ++j)
      v[j][ct] = acc[ct][j] + x[(size_t)(r0 + g * 4 + j) * 64 + ct * 16 + c];
  float sum[4], sq[4];
#pragma unroll
  for (int j = 0; j < 4; ++j) sum[j] = (v[j][0] + v[j][1]) + (v[j][2] + v[j][3]);
#pragma unroll
  for (int off = 1; off < 16; off <<= 1)
#pragma unroll
    for (int j = 0; j < 4; ++j) sum[j] += __shfl_xor(sum[j], off, 64);
#pragma unroll
  for (int j = 0; j < 4; ++j) {
    float mu = sum[j] * 0.015625f;
#pragma unroll
    for (int ct = 0; ct < 4; ++ct) v[j][ct] -= mu;
    sq[j] = (v[j][0] * v[j][0] + v[j][1] * v[j][1]) + (v[j][2] * v[j][2] + v[j][3] * v[j][3]);
  }
#pragma unroll
  for (int off = 1; off < 16; off <<= 1)
#pragma unroll
    for (int j = 0; j < 4; ++j) sq[j] += __shfl_xor(sq[j], off, 64);
#pragma unroll
  for (int j = 0; j < 4; ++j) {
    float rstd = rsqrtf(sq[j] * 0.015625f + 1e-5f);
#pragma unroll
    for (int ct = 0; ct < 4; ++ct) {
      float r = v[j][ct] * rstd;
      size_t idx = (size_t)(r0 + g * 4 + j) * 64 + ct * 16 + c;
      x[idx] = r;
      xb[idx] = f2bf(r);
    }
  }
}

// d_out is FLOAT32 (reference output dtype)
__global__ void __launch_bounds__(256) k_out(const float* __restrict__ x, float* __restrict__ out) {
  int i = blockIdx.x * 256 + threadIdx.x;
  out[i] = x[i];
}

} // namespace

extern "C" void kernel_launch(void* const* d_in, const int* in_sizes, int n_in,
                              void* d_out, int out_size, void* d_ws, size_t ws_size,
                              hipStream_t stream) {
  const int* enc = (const int*)d_in[0];
  const int* deg = (const int*)d_in[1];
  const int* MD  = (const int*)d_in[2];
  const float* semb = (const float*)d_in[3];
  const float* demb = (const float*)d_in[4];
  const float* memb = (const float*)d_in[5];
  const float* Wq = (const float*)d_in[6];
  const float* Wk = (const float*)d_in[7];
  const float* Wv = (const float*)d_in[8];
  const float* Wo = (const float*)d_in[9];
  const float* W1 = (const float*)d_in[10];
  const float* W2 = (const float*)d_in[11];

  // ---- workspace layout (~106 MB) ----
  char* p = (char*)d_ws;
  float*    x    = (float*)p;     p += (size_t)TT * DM * 4;        // residual stream, f32
  uint16_t* xb   = (uint16_t*)p;  p += (size_t)TT * DM * 2;        // bf16 shadow of x
  uint16_t* qpad = (uint16_t*)p;  p += (size_t)BB * 4 * 128 * 32 * 2;  // [bh][128][32] (pad zeroed)
  uint16_t* kpad = (uint16_t*)p;  p += (size_t)BB * 4 * 128 * 32 * 2;
  uint16_t* vt   = (uint16_t*)p;  p += (size_t)BB * 4 * 16 * 128 * 2;  // [bh][16][128] = V^T
  uint16_t* ctx  = (uint16_t*)p;  p += (size_t)TT * DM * 2;
  uint16_t* hid  = (uint16_t*)p;  p += (size_t)TT * DFF * 2;
  uint16_t* biasT = (uint16_t*)p; p += (size_t)BB * 4 * LL * LL * 2;   // [b][h][r][kk] bf16
  uint16_t* wtqkv = (uint16_t*)p; p += (size_t)NL * 192 * 64 * 2;  // [l][c:192][k:64]
  uint16_t* wto   = (uint16_t*)p; p += (size_t)NL * 64 * 64 * 2;   // [l][c:64][k:64]
  uint16_t* wt1   = (uint16_t*)p; p += (size_t)NL * 512 * 64 * 2;  // [l][c:512][k:64]
  uint16_t* wt2   = (uint16_t*)p; p += (size_t)NL * 64 * 512 * 2;  // [l][c:64][k:512]
  (void)ws_size; (void)in_sizes; (void)n_in; (void)out_size;

  // ---- setup ----
  // zero qpad+kpad (16.8 MB contiguous) so pad cols 16..31 are 0 every call
  k_zero<<<(int)(((size_t)BB * 4 * 128 * 32 * 2 * 2) / 16 / 256), 256, 0, stream>>>((uint4*)qpad);
  k_embed<<<TT * DM / 256, 256, 0, stream>>>(enc, deg, semb, demb, x, xb);
  k_trans<<<NL * 64 * 64 / 256, 256, 0, stream>>>(Wq, wtqkv, 64, 64, 192 * 64, 0);
  k_trans<<<NL * 64 * 64 / 256, 256, 0, stream>>>(Wk, wtqkv, 64, 64, 192 * 64, 64);
  k_trans<<<NL * 64 * 64 / 256, 256, 0, stream>>>(Wv, wtqkv, 64, 64, 192 * 64, 128);
  k_trans<<<NL * 64 * 64 / 256, 256, 0, stream>>>(Wo, wto, 64, 64, 64 * 64, 0);
  k_trans<<<NL * 64 * 512 / 256, 256, 0, stream>>>(W1, wt1, 64, 512, 512 * 64, 0);
  k_trans<<<NL * 512 * 64 / 256, 256, 0, stream>>>(W2, wt2, 512, 64, 64 * 512, 0);
  k_bias2<<<BB * LL * LL / 256, 256, 0, stream>>>(MD, memb, enc, biasT);

  // ---- layers ----
  for (int i = 0; i < NL; ++i) {
    k_qkvg<<<dim3(TT / 16 / 4, 3), 256, 0, stream>>>(xb, wtqkv + (size_t)i * 192 * 64, qpad, kpad, vt);
    k_attn<<<BB * 4, 256, 0, stream>>>(qpad, kpad, vt, biasT, ctx);
    k_oproj_ln<<<TT / 16 / 4, 256, 0, stream>>>(ctx, wto + (size_t)i * 64 * 64, x, xb);
    k_gemm64<4, 2, true><<<dim3(TT / 32 / 4, 8), 256, 0, stream>>>(xb, wt1 + (size_t)i * 512 * 64, hid, 512, 0);
    k_ffn2_ln<<<TT / 16 / 4, 256, 0, stream>>>(hid, wt2 + (size_t)i * 64 * 512, x, xb);
  }
  k_out<<<TT * DM / 256, 256, 0, stream>>>(x, (float*)d_out);
}

// Round 7
// 389.314 us; speedup vs baseline: 6.4066x; 1.4090x over previous
//
#include <hip/hip_runtime.h>
#include <hip/hip_bf16.h>
#include <stdint.h>

#define DI __device__ __forceinline__

namespace {

constexpr int BB  = 256;   // batch
constexpr int LL  = 128;   // seq len
constexpr int DM  = 64;    // d_model
constexpr int DFF = 512;   // ffn dim
constexpr int NL  = 6;     // layers
constexpr int TT  = BB * LL;  // 32768 tokens

typedef __attribute__((ext_vector_type(8))) short bf16x8;   // MFMA A/B frag (4 VGPR)
typedef __attribute__((ext_vector_type(4))) float f32x4;    // MFMA C/D frag

// ---------- bf16 helpers ----------
DI float bf2f(uint16_t u) { union { uint32_t i; float f; } w; w.i = (uint32_t)u << 16; return w.f; }
DI uint16_t f2bf(float f) {
  union { float f; uint32_t i; } w; w.f = f;
  uint32_t r = (w.i + 0x7fffu + ((w.i >> 16) & 1u)) >> 16;  // RNE
  return (uint16_t)r;
}
DI uint32_t pack2(float a, float b) { return (uint32_t)f2bf(a) | ((uint32_t)f2bf(b) << 16); }

// fragment load: lane l reads 8 bf16 at row (l&15), k-offset (l>>4)*8 of a row-major [16 x ld] tile
DI bf16x8 fragld(const uint16_t* __restrict__ base, int ld, int lane) {
  return *(const bf16x8*)(base + (size_t)(lane & 15) * ld + (lane >> 4) * 8);
}
DI f32x4 MFMA(bf16x8 a, bf16x8 b, f32x4 c) {
  return __builtin_amdgcn_mfma_f32_16x16x32_bf16(a, b, c, 0, 0, 0);
}

// ---------- setup kernels ----------
// x[t][d] = src_emb[enc[t]][d] + deg_emb[deg[t]][d] + pe[l][d]; also bf16 shadow xb
__global__ void __launch_bounds__(256) k_embed(const int* __restrict__ enc, const int* __restrict__ deg,
    const float* __restrict__ semb, const float* __restrict__ demb,
    float* __restrict__ x, uint16_t* __restrict__ xb) {
  int idx = blockIdx.x * 256 + threadIdx.x;   // T*64
  int t = idx >> 6, d = idx & 63;
  int l = t & (LL - 1);
  float e = (float)(d & ~1) * -0.14391156831212787f;   // -ln(10000)/64
  float ang = (float)l * __expf(e);
  float pe = (d & 1) ? __cosf(ang) : __sinf(ang);
  float v = semb[enc[t] * DM + d] + demb[deg[t] * DM + d] + pe;
  x[idx] = v;
  xb[idx] = f2bf(v);
}

// wt[mat][colOff + c][k] = bf16(w[mat][k][c])  (transpose + bf16, [N x K] per matrix)
__global__ void __launch_bounds__(256) k_trans(const float* __restrict__ w, uint16_t* __restrict__ wt,
    int K, int O, int dstStride, int colOff) {
  int idx = blockIdx.x * 256 + threadIdx.x;   // nmat*K*O
  int KO = K * O;
  int mat = idx / KO;
  int rem = idx - mat * KO;
  int c = rem / K;
  int k = rem - c * K;
  wt[(size_t)mat * dstStride + (size_t)(colOff + c) * K + k] = f2bf(w[((size_t)mat * K + k) * O + c]);
}

// biasT[b][h][r][kk] bf16 = mask(kk) ? -1e9 : md_emb[MD[b,r,kk]][h]   (layer-invariant)
__global__ void __launch_bounds__(256) k_bias2(const int* __restrict__ MD, const float* __restrict__ memb,
    const int* __restrict__ enc, uint16_t* __restrict__ biasT) {
  int o = blockIdx.x * 256 + threadIdx.x;   // BB*LL*LL
  int b  = o >> 14;
  int r  = (o >> 7) & (LL - 1);
  int kk = o & (LL - 1);
  bool mask = (enc[b * LL + kk] == 0);
  int md = MD[o];
  float4 m = *(const float4*)(memb + md * 4);
  float mv[4] = {m.x, m.y, m.z, m.w};
#pragma unroll
  for (int h = 0; h < 4; ++h) {
    uint16_t v = mask ? (uint16_t)0xce6eu : f2bf(mv[h]);
    biasT[(((size_t)(b * 4 + h) * LL) + r) * LL + kk] = v;
  }
}

// ---------- LN helper: v[j][ct] over a 16-row tile (rows spread over lanes sharing g) ----------
DI void ln_write(float (&v)[4][4], float (&xfh)[4][4], uint16_t* __restrict__ xls,
                 int r0, int g, int c) {
  float sum[4], sq[4];
#pragma unroll
  for (int j = 0; j < 4; ++j) sum[j] = (v[j][0] + v[j][1]) + (v[j][2] + v[j][3]);
#pragma unroll
  for (int off = 1; off < 16; off <<= 1)
#pragma unroll
    for (int j = 0; j < 4; ++j) sum[j] += __shfl_xor(sum[j], off, 64);
#pragma unroll
  for (int j = 0; j < 4; ++j) {
    float mu = sum[j] * 0.015625f;
#pragma unroll
    for (int ct = 0; ct < 4; ++ct) v[j][ct] -= mu;
    sq[j] = (v[j][0] * v[j][0] + v[j][1] * v[j][1]) + (v[j][2] * v[j][2] + v[j][3] * v[j][3]);
  }
#pragma unroll
  for (int off = 1; off < 16; off <<= 1)
#pragma unroll
    for (int j = 0; j < 4; ++j) sq[j] += __shfl_xor(sq[j], off, 64);
#pragma unroll
  for (int j = 0; j < 4; ++j) {
    float rstd = rsqrtf(sq[j] * 0.015625f + 1e-5f);
#pragma unroll
    for (int ct = 0; ct < 4; ++ct) {
      float r = v[j][ct] * rstd;
      xfh[ct][j] = r;
      xls[(r0 + g * 4 + j) * 72 + ct * 16 + c] = f2bf(r);
    }
  }
}

// ---------- megakernel: one workgroup per b, all 6 layers ----------
// LDS map (bytes):
//   xls   [128][72] bf16 @ 0       (18432)
//   ctxl  [128][72] bf16 @ 18432   (18432)
//   per-wave attn region @ 36864 + w*28928:
//     qls [128][40] @ +0     (10240)   (cols 16..31 zero-padded)
//     kls [128][40] @ +10240 (10240)
//     vtl [16][136] @ +20480 (4352)
//     ptl 16x256B swizzled @ +24832 (4096)
//   hid [16][520] bf16 aliases per-wave region @ +0 (16640) -- FFN phase only
__global__ void __launch_bounds__(256, 1) k_mega(
    const float* __restrict__ x0, const uint16_t* __restrict__ xb0,
    const uint16_t* __restrict__ biasT,
    const uint16_t* __restrict__ wtqkv, const uint16_t* __restrict__ wto,
    const uint16_t* __restrict__ wt1, const uint16_t* __restrict__ wt2,
    float* __restrict__ out) {
  __shared__ __align__(16) char LDSB[152576];
  int tid = threadIdx.x;
  int w = tid >> 6, lane = tid & 63;
  int g = lane >> 4, c = lane & 15;
  int b = blockIdx.x;

  uint16_t* xls  = (uint16_t*)(LDSB);
  uint16_t* ctxl = (uint16_t*)(LDSB + 18432);
  char* awr = LDSB + 36864 + w * 28928;
  uint16_t* qls = (uint16_t*)(awr);
  uint16_t* kls = (uint16_t*)(awr + 10240);
  uint16_t* vtl = (uint16_t*)(awr + 20480);
  char*     ptl = awr + 24832;
  uint16_t* hidl = (uint16_t*)(awr);          // alias (FFN phase)

  // ---- load state: residual regs (f32, C-frag layout) + xls (bf16) ----
  float xf[2][4][4];
  const float* xrow = x0 + (size_t)b * LL * DM;
#pragma unroll
  for (int hh = 0; hh < 2; ++hh)
#pragma unroll
    for (int ct = 0; ct < 4; ++ct)
#pragma unroll
      for (int j = 0; j < 4; ++j)
        xf[hh][ct][j] = xrow[(w * 32 + hh * 16 + g * 4 + j) * DM + ct * 16 + c];
  const uint16_t* xbrow = xb0 + (size_t)b * LL * DM;
#pragma unroll
  for (int m = 0; m < 4; ++m) {
    int u = tid * 4 + m;            // 0..1023 units of 8 elems
    int r = u >> 3, col = (u & 7) * 8;
    *(bf16x8*)(xls + r * 72 + col) = *(const bf16x8*)(xbrow + r * DM + col);
  }
  __syncthreads();

  for (int li = 0; li < NL; ++li) {
    // ---- zero q/k pad cols (bytes 32..63 of each 80B row), wave-local ----
#pragma unroll
    for (int m = 0; m < 8; ++m) {
      int unit = lane + m * 64;                  // 0..511
      uint16_t* base = (unit & 256) ? kls : qls;
      int r = (unit >> 1) & 127, hf = unit & 1;
      *(uint4*)((char*)base + r * 80 + 32 + hf * 16) = uint4{0, 0, 0, 0};
    }

    // ---- QKV: wave w computes Q/K/V of head w for all 128 rows ----
    const uint16_t* Wl = wtqkv + (size_t)li * 192 * 64;
    const uint16_t* Wqh = Wl + (16 * w) * 64;
    const uint16_t* Wkh = Wl + (64 + 16 * w) * 64;
    const uint16_t* Wvh = Wl + (128 + 16 * w) * 64;
    bf16x8 bq0 = fragld(Wqh, 64, lane), bq1 = fragld(Wqh + 32, 64, lane);
    bf16x8 bk0 = fragld(Wkh, 64, lane), bk1 = fragld(Wkh + 32, 64, lane);
    bf16x8 bv0 = fragld(Wvh, 64, lane), bv1 = fragld(Wvh + 32, 64, lane);
#pragma unroll
    for (int rt = 0; rt < 8; ++rt) {
      bf16x8 a0 = fragld(xls + rt * 16 * 72, 72, lane);
      bf16x8 a1 = fragld(xls + rt * 16 * 72 + 32, 72, lane);
      f32x4 aq = {0,0,0,0}, ak = {0,0,0,0}, av = {0,0,0,0};
      aq = MFMA(a0, bq0, aq); aq = MFMA(a1, bq1, aq);
      ak = MFMA(a0, bk0, ak); ak = MFMA(a1, bk1, ak);
      av = MFMA(a0, bv0, av); av = MFMA(a1, bv1, av);
      int r = rt * 16 + g * 4;
#pragma unroll
      for (int j = 0; j < 4; ++j) {
        qls[(r + j) * 40 + c] = f2bf(aq[j]);
        kls[(r + j) * 40 + c] = f2bf(ak[j]);
      }
      uint2 pk; pk.x = pack2(av[0], av[1]); pk.y = pack2(av[2], av[3]);
      *(uint2*)(vtl + c * 136 + r) = pk;       // V^T [d][kk]
    }

    // ---- attention (wave-local: head w) ----
    bf16x8 kf[8], vf[4];
#pragma unroll
    for (int ct = 0; ct < 8; ++ct) kf[ct] = fragld(kls + ct * 16 * 40, 40, lane);
#pragma unroll
    for (int kc = 0; kc < 4; ++kc) vf[kc] = fragld(vtl + kc * 32, 136, lane);
    const uint16_t* bb = biasT + (((size_t)b * 4 + w) * LL) * LL;
#pragma unroll 2
    for (int rt = 0; rt < 8; ++rt) {
      bf16x8 qf = fragld(qls + rt * 16 * 40, 40, lane);
      f32x4 s[8];
#pragma unroll
      for (int ct = 0; ct < 8; ++ct) s[ct] = MFMA(qf, kf[ct], (f32x4){0.f, 0.f, 0.f, 0.f});
      // stage bias tile (coalesced) into swizzled ptl
      {
        int rl = lane >> 2, seg = lane & 3;
        const uint16_t* gsrc = bb + (rt * 16 + rl) * LL + seg * 32;
#pragma unroll
        for (int m = 0; m < 4; ++m)
          *(bf16x8*)(ptl + rl * 256 + ((seg * 64 + m * 16) ^ ((rl & 7) << 4))) =
              *(const bf16x8*)(gsrc + m * 8);
      }
      float rs[4] = {0.f, 0.f, 0.f, 0.f};
#pragma unroll
      for (int ct = 0; ct < 8; ++ct) {
        int kk = ct * 16 + c;
#pragma unroll
        for (int j = 0; j < 4; ++j) {
          int row = g * 4 + j;
          char* addr = ptl + row * 256 + ((kk * 2) ^ ((row & 7) << 4));
          float bias = bf2f(*(uint16_t*)addr);
          float p = __expf(fmaf(s[ct][j], 0.25f, bias));
          rs[j] += p;
          *(uint16_t*)addr = f2bf(p);
        }
      }
#pragma unroll
      for (int off = 1; off < 16; off <<= 1)
#pragma unroll
        for (int j = 0; j < 4; ++j) rs[j] += __shfl_xor(rs[j], off, 64);
      float inv[4];
#pragma unroll
      for (int j = 0; j < 4; ++j) inv[j] = 1.0f / rs[j];
      f32x4 o = {0.f, 0.f, 0.f, 0.f};
#pragma unroll
      for (int kc = 0; kc < 4; ++kc) {
        bf16x8 af = *(const bf16x8*)(ptl + c * 256 + ((kc * 64 + g * 16) ^ ((c & 7) << 4)));
        o = MFMA(af, vf[kc], o);
      }
      int r = rt * 16 + g * 4;
#pragma unroll
      for (int j = 0; j < 4; ++j)
        ctxl[(r + j) * 72 + w * 16 + c] = f2bf(o[j] * inv[j]);
    }
    __syncthreads();

    // ---- O-proj + residual + LN (wave owns rows 32w..32w+31) ----
    const uint16_t* Wol = wto + (size_t)li * 64 * 64;
    bf16x8 bo[4][2];
#pragma unroll
    for (int ct = 0; ct < 4; ++ct) {
      bo[ct][0] = fragld(Wol + ct * 16 * 64, 64, lane);
      bo[ct][1] = fragld(Wol + ct * 16 * 64 + 32, 64, lane);
    }
#pragma unroll
    for (int hh = 0; hh < 2; ++hh) {
      int r0 = w * 32 + hh * 16;
      bf16x8 a0 = fragld(ctxl + r0 * 72, 72, lane);
      bf16x8 a1 = fragld(ctxl + r0 * 72 + 32, 72, lane);
      float v[4][4];
#pragma unroll
      for (int ct = 0; ct < 4; ++ct) {
        f32x4 acc = {0,0,0,0};
        acc = MFMA(a0, bo[ct][0], acc);
        acc = MFMA(a1, bo[ct][1], acc);
#pragma unroll
        for (int j = 0; j < 4; ++j) v[j][ct] = acc[j] + xf[hh][ct][j];
      }
      ln_write(v, xf[hh], xls, r0, g, c);
    }

    // ---- FFN (wave-local rows; hid in LDS alias) ----
    const uint16_t* W1l = wt1 + (size_t)li * 512 * 64;
    const uint16_t* W2l = wt2 + (size_t)li * 64 * 512;
#pragma unroll
    for (int hh = 0; hh < 2; ++hh) {
      int r0 = w * 32 + hh * 16;
      bf16x8 a0 = fragld(xls + r0 * 72, 72, lane);
      bf16x8 a1 = fragld(xls + r0 * 72 + 32, 72, lane);
#pragma unroll 4
      for (int ct = 0; ct < 32; ++ct) {
        f32x4 acc = {0,0,0,0};
        acc = MFMA(a0, fragld(W1l + ct * 16 * 64, 64, lane), acc);
        acc = MFMA(a1, fragld(W1l + ct * 16 * 64 + 32, 64, lane), acc);
        int rr = g * 4;
#pragma unroll
        for (int j = 0; j < 4; ++j)
          hidl[(rr + j) * 520 + ct * 16 + c] = f2bf(fmaxf(acc[j], 0.f));
      }
      f32x4 acc2[4] = {{0,0,0,0},{0,0,0,0},{0,0,0,0},{0,0,0,0}};
#pragma unroll 4
      for (int kc = 0; kc < 16; ++kc) {
        bf16x8 a = fragld(hidl + kc * 32, 520, lane);
#pragma unroll
        for (int ct = 0; ct < 4; ++ct)
          acc2[ct] = MFMA(a, fragld(W2l + ct * 16 * 512 + kc * 32, 512, lane), acc2[ct]);
      }
      float v[4][4];
#pragma unroll
      for (int ct = 0; ct < 4; ++ct)
#pragma unroll
        for (int j = 0; j < 4; ++j) v[j][ct] = acc2[ct][j] + xf[hh][ct][j];
      ln_write(v, xf[hh], xls, r0, g, c);
    }
    __syncthreads();
  }

  // ---- write f32 output ----
  float* orow = out + (size_t)b * LL * DM;
#pragma unroll
  for (int hh = 0; hh < 2; ++hh)
#pragma unroll
    for (int ct = 0; ct < 4; ++ct)
#pragma unroll
      for (int j = 0; j < 4; ++j)
        orow[(w * 32 + hh * 16 + g * 4 + j) * DM + ct * 16 + c] = xf[hh][ct][j];
}

} // namespace

extern "C" void kernel_launch(void* const* d_in, const int* in_sizes, int n_in,
                              void* d_out, int out_size, void* d_ws, size_t ws_size,
                              hipStream_t stream) {
  const int* enc = (const int*)d_in[0];
  const int* deg = (const int*)d_in[1];
  const int* MD  = (const int*)d_in[2];
  const float* semb = (const float*)d_in[3];
  const float* demb = (const float*)d_in[4];
  const float* memb = (const float*)d_in[5];
  const float* Wq = (const float*)d_in[6];
  const float* Wk = (const float*)d_in[7];
  const float* Wv = (const float*)d_in[8];
  const float* Wo = (const float*)d_in[9];
  const float* W1 = (const float*)d_in[10];
  const float* W2 = (const float*)d_in[11];

  // ---- workspace layout (~47 MB) ----
  char* p = (char*)d_ws;
  float*    x    = (float*)p;     p += (size_t)TT * DM * 4;         // embed output, f32
  uint16_t* xb   = (uint16_t*)p;  p += (size_t)TT * DM * 2;         // bf16 shadow
  uint16_t* biasT = (uint16_t*)p; p += (size_t)BB * 4 * LL * LL * 2; // [b][h][r][kk]
  uint16_t* wtqkv = (uint16_t*)p; p += (size_t)NL * 192 * 64 * 2;   // [l][c:192][k:64]
  uint16_t* wto   = (uint16_t*)p; p += (size_t)NL * 64 * 64 * 2;    // [l][c:64][k:64]
  uint16_t* wt1   = (uint16_t*)p; p += (size_t)NL * 512 * 64 * 2;   // [l][c:512][k:64]
  uint16_t* wt2   = (uint16_t*)p; p += (size_t)NL * 64 * 512 * 2;   // [l][c:64][k:512]
  (void)ws_size; (void)in_sizes; (void)n_in; (void)out_size;

  // ---- setup ----
  k_embed<<<TT * DM / 256, 256, 0, stream>>>(enc, deg, semb, demb, x, xb);
  k_trans<<<NL * 64 * 64 / 256, 256, 0, stream>>>(Wq, wtqkv, 64, 64, 192 * 64, 0);
  k_trans<<<NL * 64 * 64 / 256, 256, 0, stream>>>(Wk, wtqkv, 64, 64, 192 * 64, 64);
  k_trans<<<NL * 64 * 64 / 256, 256, 0, stream>>>(Wv, wtqkv, 64, 64, 192 * 64, 128);
  k_trans<<<NL * 64 * 64 / 256, 256, 0, stream>>>(Wo, wto, 64, 64, 64 * 64, 0);
  k_trans<<<NL * 64 * 512 / 256, 256, 0, stream>>>(W1, wt1, 64, 512, 512 * 64, 0);
  k_trans<<<NL * 512 * 64 / 256, 256, 0, stream>>>(W2, wt2, 512, 64, 64 * 512, 0);
  k_bias2<<<BB * LL * LL / 256, 256, 0, stream>>>(MD, memb, enc, biasT);

  // ---- whole network: one workgroup per batch element ----
  k_mega<<<BB, 256, 0, stream>>>(x, xb, biasT, wtqkv, wto, wt1, wt2, (float*)d_out);
}

// Round 8
// 306.817 us; speedup vs baseline: 8.1293x; 1.2689x over previous
//
#include <hip/hip_runtime.h>
#include <hip/hip_bf16.h>
#include <stdint.h>

#define DI __device__ __forceinline__

namespace {

constexpr int BB  = 256;   // batch
constexpr int LL  = 128;   // seq len
constexpr int DM  = 64;    // d_model
constexpr int DFF = 512;   // ffn dim
constexpr int NL  = 6;     // layers
constexpr int TT  = BB * LL;  // 32768 tokens

typedef __attribute__((ext_vector_type(8))) short bf16x8;   // MFMA A/B frag (4 VGPR)
typedef __attribute__((ext_vector_type(4))) float f32x4;    // MFMA C/D frag

// ---------- bf16 helpers ----------
DI float bf2f(uint16_t u) { union { uint32_t i; float f; } w; w.i = (uint32_t)u << 16; return w.f; }
DI uint16_t f2bf(float f) {
  union { float f; uint32_t i; } w; w.f = f;
  uint32_t r = (w.i + 0x7fffu + ((w.i >> 16) & 1u)) >> 16;  // RNE
  return (uint16_t)r;
}
DI uint32_t pack2(float a, float b) { return (uint32_t)f2bf(a) | ((uint32_t)f2bf(b) << 16); }

// fragment load: lane l reads 8 bf16 at row (l&15), k-offset (l>>4)*8 of a row-major [16 x ld] tile
DI bf16x8 fragld(const uint16_t* __restrict__ base, int ld, int lane) {
  return *(const bf16x8*)(base + (size_t)(lane & 15) * ld + (lane >> 4) * 8);
}
DI f32x4 MFMA(bf16x8 a, bf16x8 b, f32x4 c) {
  return __builtin_amdgcn_mfma_f32_16x16x32_bf16(a, b, c, 0, 0, 0);
}

// ---------- setup kernels ----------
__global__ void __launch_bounds__(256) k_embed(const int* __restrict__ enc, const int* __restrict__ deg,
    const float* __restrict__ semb, const float* __restrict__ demb,
    float* __restrict__ x, uint16_t* __restrict__ xb) {
  int idx = blockIdx.x * 256 + threadIdx.x;   // T*64
  int t = idx >> 6, d = idx & 63;
  int l = t & (LL - 1);
  float e = (float)(d & ~1) * -0.14391156831212787f;   // -ln(10000)/64
  float ang = (float)l * __expf(e);
  float pe = (d & 1) ? __cosf(ang) : __sinf(ang);
  float v = semb[enc[t] * DM + d] + demb[deg[t] * DM + d] + pe;
  x[idx] = v;
  xb[idx] = f2bf(v);
}

__global__ void __launch_bounds__(256) k_trans(const float* __restrict__ w, uint16_t* __restrict__ wt,
    int K, int O, int dstStride, int colOff) {
  int idx = blockIdx.x * 256 + threadIdx.x;   // nmat*K*O
  int KO = K * O;
  int mat = idx / KO;
  int rem = idx - mat * KO;
  int c = rem / K;
  int k = rem - c * K;
  wt[(size_t)mat * dstStride + (size_t)(colOff + c) * K + k] = f2bf(w[((size_t)mat * K + k) * O + c]);
}

// biasT[b][h][r][kk] bf16 = mask(kk) ? -1e9 : md_emb[MD[b,r,kk]][h]   (layer-invariant)
__global__ void __launch_bounds__(256) k_bias2(const int* __restrict__ MD, const float* __restrict__ memb,
    const int* __restrict__ enc, uint16_t* __restrict__ biasT) {
  int o = blockIdx.x * 256 + threadIdx.x;   // BB*LL*LL
  int b  = o >> 14;
  int r  = (o >> 7) & (LL - 1);
  int kk = o & (LL - 1);
  bool mask = (enc[b * LL + kk] == 0);
  int md = MD[o];
  float4 m = *(const float4*)(memb + md * 4);
  float mv[4] = {m.x, m.y, m.z, m.w};
#pragma unroll
  for (int h = 0; h < 4; ++h) {
    uint16_t v = mask ? (uint16_t)0xce6eu : f2bf(mv[h]);
    biasT[(((size_t)(b * 4 + h) * LL) + r) * LL + kk] = v;
  }
}

// ---------- LN helper: v[j][ct] over one 16-row tile ----------
DI void ln_write(float (&v)[4][4], float (&xfh)[4][4], uint16_t* __restrict__ xls,
                 int r0, int g, int c) {
  float sum[4], sq[4];
#pragma unroll
  for (int j = 0; j < 4; ++j) sum[j] = (v[j][0] + v[j][1]) + (v[j][2] + v[j][3]);
#pragma unroll
  for (int off = 1; off < 16; off <<= 1)
#pragma unroll
    for (int j = 0; j < 4; ++j) sum[j] += __shfl_xor(sum[j], off, 64);
#pragma unroll
  for (int j = 0; j < 4; ++j) {
    float mu = sum[j] * 0.015625f;
#pragma unroll
    for (int ct = 0; ct < 4; ++ct) v[j][ct] -= mu;
    sq[j] = (v[j][0] * v[j][0] + v[j][1] * v[j][1]) + (v[j][2] * v[j][2] + v[j][3] * v[j][3]);
  }
#pragma unroll
  for (int off = 1; off < 16; off <<= 1)
#pragma unroll
    for (int j = 0; j < 4; ++j) sq[j] += __shfl_xor(sq[j], off, 64);
#pragma unroll
  for (int j = 0; j < 4; ++j) {
    float rstd = rsqrtf(sq[j] * 0.015625f + 1e-5f);
#pragma unroll
    for (int ct = 0; ct < 4; ++ct) {
      float r = v[j][ct] * rstd;
      xfh[ct][j] = r;
      xls[(r0 + g * 4 + j) * 72 + ct * 16 + c] = f2bf(r);
    }
  }
}

// ---------- megakernel: one workgroup (512 thr, 8 waves) per b, all 6 layers ----------
// Wave roles: QKV/attn: wave = (head h = w8&3, half = w8>>2) -> 64 Q rows; K/V shared per head.
//             O-proj/FFN: wave w8 owns rows w8*16..+15.
// LDS map (bytes):
//   xls  [128][72]           @ 0       (18432)  persistent
//   attn phase:
//     kls  4x[128][40]       @ 18432   (40960)  (cols 16..31 zero)
//     vtl  4x[16][136]       @ 59392   (17408)
//     qsc  8x[16][40]        @ 76800   (10240)  (cols 16..31 zero)
//     ptl  8x 4096B swizzled @ 87040   (32768)
//   O-proj/FFN phase (aliases attn scratch):
//     ctxl [128][72]         @ 18432   (18432)
//     hid  8x[16][264]       @ 36864   (67584)
__global__ void __launch_bounds__(512, 1) k_mega(
    const float* __restrict__ x0, const uint16_t* __restrict__ xb0,
    const uint16_t* __restrict__ biasT,
    const uint16_t* __restrict__ wtqkv, const uint16_t* __restrict__ wto,
    const uint16_t* __restrict__ wt1, const uint16_t* __restrict__ wt2,
    float* __restrict__ out) {
  __shared__ __align__(16) char LDSB[119808];
  int tid = threadIdx.x;
  int w8 = tid >> 6, lane = tid & 63;
  int g = lane >> 4, c = lane & 15;
  int h = w8 & 3, half = w8 >> 2;
  int b = blockIdx.x;

  uint16_t* xls  = (uint16_t*)(LDSB);
  uint16_t* klsA = (uint16_t*)(LDSB + 18432);            // all heads
  uint16_t* klsh = (uint16_t*)(LDSB + 18432 + h * 10240);
  uint16_t* vtlh = (uint16_t*)(LDSB + 59392 + h * 4352);
  uint16_t* qsc  = (uint16_t*)(LDSB + 76800 + w8 * 1280);
  char*     ptl  = LDSB + 87040 + w8 * 4096;
  uint16_t* ctxl = (uint16_t*)(LDSB + 18432);
  uint16_t* hidl = (uint16_t*)(LDSB + 36864 + w8 * 8448);

  // ---- residual regs: rows w8*16..+15 (C-frag layout) ----
  float xf[4][4];
  const float* xrow = x0 + ((size_t)b * LL + w8 * 16) * DM;
#pragma unroll
  for (int ct = 0; ct < 4; ++ct)
#pragma unroll
    for (int j = 0; j < 4; ++j)
      xf[ct][j] = xrow[(g * 4 + j) * DM + ct * 16 + c];
  // ---- xls fill (whole b) ----
  const uint16_t* xbrow = xb0 + (size_t)b * LL * DM;
#pragma unroll
  for (int m = 0; m < 2; ++m) {
    int u = tid * 2 + m;            // 0..1023 units of 8 elems
    int r = u >> 3, col = (u & 7) * 8;
    *(bf16x8*)(xls + r * 72 + col) = *(const bf16x8*)(xbrow + r * DM + col);
  }
  __syncthreads();

  for (int li = 0; li < NL; ++li) {
    // ---- re-zero pad cols (kls all heads; own qsc) — aliased regions were clobbered by FFN ----
#pragma unroll
    for (int m = 0; m < 2; ++m) {
      int idx = tid * 2 + m;                       // 0..1023
      int head = idx >> 8, r = (idx >> 1) & 127, s = idx & 1;
      *(uint4*)(klsA + head * 5120 + r * 40 + 16 + s * 8) = uint4{0, 0, 0, 0};
    }
    if (lane < 32) {
      int r = lane >> 1, s = lane & 1;
      *(uint4*)(qsc + r * 40 + 16 + s * 8) = uint4{0, 0, 0, 0};
    }

    // ---- QKV: wave (h, half) computes q/k/v of head h for rows half*64..+63 ----
    const uint16_t* Wl = wtqkv + (size_t)li * 192 * 64;
    bf16x8 bq0 = fragld(Wl + (h * 16) * 64, 64, lane);
    bf16x8 bq1 = fragld(Wl + (h * 16) * 64 + 32, 64, lane);
    bf16x8 bk0 = fragld(Wl + (64 + h * 16) * 64, 64, lane);
    bf16x8 bk1 = fragld(Wl + (64 + h * 16) * 64 + 32, 64, lane);
    bf16x8 bv0 = fragld(Wl + (128 + h * 16) * 64, 64, lane);
    bf16x8 bv1 = fragld(Wl + (128 + h * 16) * 64 + 32, 64, lane);
    uint2 qreg[4];
#pragma unroll
    for (int rt = 0; rt < 4; ++rt) {
      int r0 = half * 64 + rt * 16;
      bf16x8 a0 = fragld(xls + r0 * 72, 72, lane);
      bf16x8 a1 = fragld(xls + r0 * 72 + 32, 72, lane);
      f32x4 aq = {0,0,0,0}, ak = {0,0,0,0}, av = {0,0,0,0};
      aq = MFMA(a0, bq0, aq); aq = MFMA(a1, bq1, aq);
      ak = MFMA(a0, bk0, ak); ak = MFMA(a1, bk1, ak);
      av = MFMA(a0, bv0, av); av = MFMA(a1, bv1, av);
#pragma unroll
      for (int j = 0; j < 4; ++j)
        klsh[(r0 + g * 4 + j) * 40 + c] = f2bf(ak[j]);
      uint2 pk; pk.x = pack2(av[0], av[1]); pk.y = pack2(av[2], av[3]);
      *(uint2*)(vtlh + c * 136 + r0 + g * 4) = pk;     // V^T [d][kk]
      qreg[rt].x = pack2(aq[0], aq[1]); qreg[rt].y = pack2(aq[2], aq[3]);
    }
    __syncthreads();

    // ---- attention: head h, Q rows half*64..+63 ----
    bf16x8 kf[8], vf[4];
#pragma unroll
    for (int ct = 0; ct < 8; ++ct) kf[ct] = fragld(klsh + ct * 16 * 40, 40, lane);
#pragma unroll
    for (int kc = 0; kc < 4; ++kc) vf[kc] = fragld(vtlh + kc * 32, 136, lane);
    const uint16_t* bb = biasT + ((size_t)b * 4 + h) * (LL * LL);
    uint2 creg[4];
#pragma unroll 2
    for (int rt = 0; rt < 4; ++rt) {
      // q C-frag -> qsc -> A-frag
      qsc[(g * 4 + 0) * 40 + c] = (uint16_t)(qreg[rt].x & 0xffff);
      qsc[(g * 4 + 1) * 40 + c] = (uint16_t)(qreg[rt].x >> 16);
      qsc[(g * 4 + 2) * 40 + c] = (uint16_t)(qreg[rt].y & 0xffff);
      qsc[(g * 4 + 3) * 40 + c] = (uint16_t)(qreg[rt].y >> 16);
      bf16x8 qf = fragld(qsc, 40, lane);
      f32x4 s[8];
#pragma unroll
      for (int ct = 0; ct < 8; ++ct) s[ct] = MFMA(qf, kf[ct], (f32x4){0.f, 0.f, 0.f, 0.f});
      // stage bias tile (coalesced) into swizzled ptl
      {
        int rl = lane >> 2, seg = lane & 3;
        const uint16_t* gsrc = bb + (half * 64 + rt * 16 + rl) * LL + seg * 32;
#pragma unroll
        for (int m = 0; m < 4; ++m)
          *(bf16x8*)(ptl + rl * 256 + ((seg * 64 + m * 16) ^ ((rl & 7) << 4))) =
              *(const bf16x8*)(gsrc + m * 8);
      }
      float rs[4] = {0.f, 0.f, 0.f, 0.f};
#pragma unroll
      for (int ct = 0; ct < 8; ++ct) {
        int kk = ct * 16 + c;
#pragma unroll
        for (int j = 0; j < 4; ++j) {
          int row = g * 4 + j;
          char* addr = ptl + row * 256 + ((kk * 2) ^ ((row & 7) << 4));
          float bias = bf2f(*(uint16_t*)addr);
          float p = __expf(fmaf(s[ct][j], 0.25f, bias));
          rs[j] += p;
          *(uint16_t*)addr = f2bf(p);
        }
      }
#pragma unroll
      for (int off = 1; off < 16; off <<= 1)
#pragma unroll
        for (int j = 0; j < 4; ++j) rs[j] += __shfl_xor(rs[j], off, 64);
      f32x4 o = {0.f, 0.f, 0.f, 0.f};
#pragma unroll
      for (int kc = 0; kc < 4; ++kc) {
        bf16x8 af = *(const bf16x8*)(ptl + c * 256 + ((kc * 64 + g * 16) ^ ((c & 7) << 4)));
        o = MFMA(af, vf[kc], o);
      }
      creg[rt].x = pack2(o[0] / rs[0], o[1] / rs[1]);
      creg[rt].y = pack2(o[2] / rs[2], o[3] / rs[3]);
    }
    __syncthreads();                 // all kls/vtl reads done -> ctxl may overwrite

    // ---- ctx regs -> ctxl ----
#pragma unroll
    for (int rt = 0; rt < 4; ++rt) {
      int r0 = half * 64 + rt * 16;
      ctxl[(r0 + g * 4 + 0) * 72 + h * 16 + c] = (uint16_t)(creg[rt].x & 0xffff);
      ctxl[(r0 + g * 4 + 1) * 72 + h * 16 + c] = (uint16_t)(creg[rt].x >> 16);
      ctxl[(r0 + g * 4 + 2) * 72 + h * 16 + c] = (uint16_t)(creg[rt].y & 0xffff);
      ctxl[(r0 + g * 4 + 3) * 72 + h * 16 + c] = (uint16_t)(creg[rt].y >> 16);
    }
    __syncthreads();

    // ---- O-proj + residual + LN (wave owns rows w8*16..+15) ----
    int r0 = w8 * 16;
    {
      const uint16_t* Wol = wto + (size_t)li * 64 * 64;
      bf16x8 a0 = fragld(ctxl + r0 * 72, 72, lane);
      bf16x8 a1 = fragld(ctxl + r0 * 72 + 32, 72, lane);
      float v[4][4];
#pragma unroll
      for (int ct = 0; ct < 4; ++ct) {
        f32x4 acc = {0,0,0,0};
        acc = MFMA(a0, fragld(Wol + ct * 16 * 64, 64, lane), acc);
        acc = MFMA(a1, fragld(Wol + ct * 16 * 64 + 32, 64, lane), acc);
#pragma unroll
        for (int j = 0; j < 4; ++j) v[j][ct] = acc[j] + xf[ct][j];
      }
      ln_write(v, xf, xls, r0, g, c);
    }

    // ---- FFN (wave-local rows; hid halved: 2 x 256 ffn dims) ----
    {
      const uint16_t* W1l = wt1 + (size_t)li * 512 * 64;
      const uint16_t* W2l = wt2 + (size_t)li * 64 * 512;
      bf16x8 a0 = fragld(xls + r0 * 72, 72, lane);
      bf16x8 a1 = fragld(xls + r0 * 72 + 32, 72, lane);
      f32x4 acc2[4] = {{0,0,0,0},{0,0,0,0},{0,0,0,0},{0,0,0,0}};
#pragma unroll
      for (int ffh = 0; ffh < 2; ++ffh) {
#pragma unroll 4
        for (int ct2 = 0; ct2 < 16; ++ct2) {
          int ctg = ffh * 16 + ct2;
          f32x4 acc = {0,0,0,0};
          acc = MFMA(a0, fragld(W1l + ctg * 16 * 64, 64, lane), acc);
          acc = MFMA(a1, fragld(W1l + ctg * 16 * 64 + 32, 64, lane), acc);
#pragma unroll
          for (int j = 0; j < 4; ++j)
            hidl[(g * 4 + j) * 264 + ct2 * 16 + c] = f2bf(fmaxf(acc[j], 0.f));
        }
#pragma unroll 4
        for (int kc2 = 0; kc2 < 8; ++kc2) {
          bf16x8 a = fragld(hidl + kc2 * 32, 264, lane);
#pragma unroll
          for (int ct = 0; ct < 4; ++ct)
            acc2[ct] = MFMA(a, fragld(W2l + ct * 16 * 512 + ffh * 256 + kc2 * 32, 512, lane), acc2[ct]);
        }
      }
      float v[4][4];
#pragma unroll
      for (int ct = 0; ct < 4; ++ct)
#pragma unroll
        for (int j = 0; j < 4; ++j) v[j][ct] = acc2[ct][j] + xf[ct][j];
      ln_write(v, xf, xls, r0, g, c);
    }
    __syncthreads();                 // xls fully updated before next layer's QKV
  }

  // ---- write f32 output (own rows) ----
  float* orow = out + ((size_t)b * LL + w8 * 16) * DM;
#pragma unroll
  for (int ct = 0; ct < 4; ++ct)
#pragma unroll
    for (int j = 0; j < 4; ++j)
      orow[(g * 4 + j) * DM + ct * 16 + c] = xf[ct][j];
}

} // namespace

extern "C" void kernel_launch(void* const* d_in, const int* in_sizes, int n_in,
                              void* d_out, int out_size, void* d_ws, size_t ws_size,
                              hipStream_t stream) {
  const int* enc = (const int*)d_in[0];
  const int* deg = (const int*)d_in[1];
  const int* MD  = (const int*)d_in[2];
  const float* semb = (const float*)d_in[3];
  const float* demb = (const float*)d_in[4];
  const float* memb = (const float*)d_in[5];
  const float* Wq = (const float*)d_in[6];
  const float* Wk = (const float*)d_in[7];
  const float* Wv = (const float*)d_in[8];
  const float* Wo = (const float*)d_in[9];
  const float* W1 = (const float*)d_in[10];
  const float* W2 = (const float*)d_in[11];

  // ---- workspace layout (~47 MB) ----
  char* p = (char*)d_ws;
  float*    x    = (float*)p;     p += (size_t)TT * DM * 4;         // embed output, f32
  uint16_t* xb   = (uint16_t*)p;  p += (size_t)TT * DM * 2;         // bf16 shadow
  uint16_t* biasT = (uint16_t*)p; p += (size_t)BB * 4 * LL * LL * 2; // [b][h][r][kk]
  uint16_t* wtqkv = (uint16_t*)p; p += (size_t)NL * 192 * 64 * 2;   // [l][c:192][k:64]
  uint16_t* wto   = (uint16_t*)p; p += (size_t)NL * 64 * 64 * 2;    // [l][c:64][k:64]
  uint16_t* wt1   = (uint16_t*)p; p += (size_t)NL * 512 * 64 * 2;   // [l][c:512][k:64]
  uint16_t* wt2   = (uint16_t*)p; p += (size_t)NL * 64 * 512 * 2;   // [l][c:64][k:512]
  (void)ws_size; (void)in_sizes; (void)n_in; (void)out_size;

  // ---- setup ----
  k_embed<<<TT * DM / 256, 256, 0, stream>>>(enc, deg, semb, demb, x, xb);
  k_trans<<<NL * 64 * 64 / 256, 256, 0, stream>>>(Wq, wtqkv, 64, 64, 192 * 64, 0);
  k_trans<<<NL * 64 * 64 / 256, 256, 0, stream>>>(Wk, wtqkv, 64, 64, 192 * 64, 64);
  k_trans<<<NL * 64 * 64 / 256, 256, 0, stream>>>(Wv, wtqkv, 64, 64, 192 * 64, 128);
  k_trans<<<NL * 64 * 64 / 256, 256, 0, stream>>>(Wo, wto, 64, 64, 64 * 64, 0);
  k_trans<<<NL * 64 * 512 / 256, 256, 0, stream>>>(W1, wt1, 64, 512, 512 * 64, 0);
  k_trans<<<NL * 512 * 64 / 256, 256, 0, stream>>>(W2, wt2, 512, 64, 64 * 512, 0);
  k_bias2<<<BB * LL * LL / 256, 256, 0, stream>>>(MD, memb, enc, biasT);

  // ---- whole network: one 8-wave workgroup per batch element ----
  k_mega<<<BB, 512, 0, stream>>>(x, xb, biasT, wtqkv, wto, wt1, wt2, (float*)d_out);
}